// Round 2
// baseline (714.566 us; speedup 1.0000x reference)
//
#include <hip/hip_runtime.h>
#include <hip/hip_bf16.h>
#include <math.h>

#define BB 2
#define SS 1024
#define DD 1024
#define HH 16
#define HDIM 64
#define KK 31
#define GG 4
#define EE 2
#define HIDN 2048
#define NTOK (BB*SS)
#define D3 (3*DD)

typedef unsigned short u16;
typedef __attribute__((ext_vector_type(8))) short s16x8;
typedef __attribute__((ext_vector_type(8))) unsigned short u16x8;
typedef __attribute__((ext_vector_type(4))) unsigned short u16x4;
typedef __attribute__((ext_vector_type(4))) float f32x4;
typedef __attribute__((ext_vector_type(2))) unsigned int u32x2;

__device__ __forceinline__ float gelu_f(float x) {
  return 0.5f * x * (1.0f + erff(x * 0.7071067811865475f));
}
__device__ __forceinline__ u16 f2bf(float f) {
  unsigned u = __builtin_bit_cast(unsigned, f);
  u = (u + 0x7fffu + ((u >> 16) & 1u)) >> 16;
  return (u16)u;
}
__device__ __forceinline__ float bf2f(u16 u) {
  return __builtin_bit_cast(float, ((unsigned)u) << 16);
}
__device__ __forceinline__ f32x4 MFMA16(s16x8 a, s16x8 b, f32x4 c) {
  return __builtin_amdgcn_mfma_f32_16x16x32_bf16(a, b, c, 0, 0, 0);
}
#define GLOAD16(gp, lp) __builtin_amdgcn_global_load_lds( \
    (const __attribute__((address_space(1))) void*)(gp),  \
    (__attribute__((address_space(3))) void*)(lp), 16, 0, 0)

// ---------------- LayerNorm: fp32 in -> bf16 out, one block per row ----------------
__global__ void ln_kernel(const float* __restrict__ x, const float* __restrict__ g,
                          const float* __restrict__ b, u16* __restrict__ out) {
  const int row = blockIdx.x;
  const int tid = threadIdx.x;
  __shared__ float red[4];
  const float4 v = reinterpret_cast<const float4*>(x + (size_t)row * DD)[tid];
  float s = v.x + v.y + v.z + v.w;
  s += __shfl_down(s, 32); s += __shfl_down(s, 16); s += __shfl_down(s, 8);
  s += __shfl_down(s, 4);  s += __shfl_down(s, 2);  s += __shfl_down(s, 1);
  if ((tid & 63) == 0) red[tid >> 6] = s;
  __syncthreads();
  const float mean = (red[0] + red[1] + red[2] + red[3]) * (1.0f / DD);
  __syncthreads();
  const float4 d = make_float4(v.x - mean, v.y - mean, v.z - mean, v.w - mean);
  float sq = d.x*d.x + d.y*d.y + d.z*d.z + d.w*d.w;
  sq += __shfl_down(sq, 32); sq += __shfl_down(sq, 16); sq += __shfl_down(sq, 8);
  sq += __shfl_down(sq, 4);  sq += __shfl_down(sq, 2);  sq += __shfl_down(sq, 1);
  if ((tid & 63) == 0) red[tid >> 6] = sq;
  __syncthreads();
  const float var = (red[0] + red[1] + red[2] + red[3]) * (1.0f / DD);
  const float rstd = rsqrtf(var + 1e-5f);
  const float4 gv = reinterpret_cast<const float4*>(g)[tid];
  const float4 bv = reinterpret_cast<const float4*>(b)[tid];
  u16x4 o;
  o[0] = f2bf(d.x * rstd * gv.x + bv.x);
  o[1] = f2bf(d.y * rstd * gv.y + bv.y);
  o[2] = f2bf(d.z * rstd * gv.z + bv.z);
  o[3] = f2bf(d.w * rstd * gv.w + bv.w);
  *reinterpret_cast<u16x4*>(out + (size_t)row * DD + tid * 4) = o;
}

// ---------------- conv weight reorder (per tap-pass): conv_w[o][i][k] f32 -> Wb[k-koff][o][i] bf16 ----------------
__global__ void prep_convw(const float* __restrict__ cw, u16* __restrict__ Wb,
                           int koff, int kcnt) {
  const int o = blockIdx.x;
#pragma unroll
  for (int rep = 0; rep < 4; ++rep) {
    const int i = rep * 256 + threadIdx.x;
    const float* src = cw + ((size_t)o * DD + i) * KK + koff;
    for (int k = 0; k < kcnt; ++k)
      Wb[((size_t)k * DD + o) * DD + i] = f2bf(src[k]);
  }
}

// ---------------- plain f32 -> bf16 convert ----------------
__global__ void cvt_kernel(const float* __restrict__ in, u16* __restrict__ outp, int n4) {
  const int i = blockIdx.x * 256 + threadIdx.x;
  if (i < n4) {
    const float4 v = reinterpret_cast<const float4*>(in)[i];
    u16x4 o; o[0] = f2bf(v.x); o[1] = f2bf(v.y); o[2] = f2bf(v.z); o[3] = f2bf(v.w);
    reinterpret_cast<u16x4*>(outp)[i] = o;
  }
}

// ---------------- transpose-convert: src[z][R][C] f32 -> dst[z][C][R] bf16 ----------------
__global__ void tr_kernel(const float* __restrict__ src, u16* __restrict__ dst, int R, int C) {
  __shared__ float tile[32][33];
  const int c0 = blockIdx.x * 32, r0 = blockIdx.y * 32;
  const size_t base = (size_t)blockIdx.z * R * C;
  const int tx = threadIdx.x & 31, ty = threadIdx.x >> 5;  // ty 0..7
#pragma unroll
  for (int i = 0; i < 4; ++i)
    tile[ty + i * 8][tx] = src[base + (size_t)(r0 + ty + i * 8) * C + c0 + tx];
  __syncthreads();
#pragma unroll
  for (int i = 0; i < 4; ++i)
    dst[base + (size_t)(c0 + ty + i * 8) * R + r0 + tx] = f2bf(tile[tx][ty + i * 8]);
}

// ---------------- V transpose: qkvb V-part -> Vt[b][h][d][k] bf16 ----------------
__global__ void vtr_kernel(const u16* __restrict__ qkvb, u16* __restrict__ Vt) {
  __shared__ u16 tile[32][40];
  const int k0 = blockIdx.x * 32, d0 = blockIdx.y * 32, bh = blockIdx.z;
  const int b = bh >> 4, h = bh & 15;
  const int tx = threadIdx.x & 31, ty = threadIdx.x >> 5;  // ty 0..7
#pragma unroll
  for (int i = 0; i < 4; ++i)
    tile[ty + i * 8][tx] =
        qkvb[(size_t)(b * SS + k0 + ty + i * 8) * D3 + 2 * DD + h * HDIM + d0 + tx];
  __syncthreads();
#pragma unroll
  for (int i = 0; i < 4; ++i)
    Vt[((size_t)(b * HH + h) * HDIM + d0 + ty + i * 8) * SS + k0 + tx] = tile[tx][ty + i * 8];
}

// ---------------- conv via MFMA v3: 256s x 128o block, wave 128s x 64o, two tap-passes ----------------
// 8 waves = 2(s) x 2(o) x 2(ks). K-step = 64 i per round; rounds = 4 slices x kcnt taps.
// LDS reads/MFMA = 0.375 (vs 0.5 at 64x64 tiles). B ring-4 block-shared, counted vmcnt(4).
// z=4 i-splits -> P f32 x4 partials; taps split in 2 passes (Wb' 32MB/pass), pass2 accumulates P.
__global__ __launch_bounds__(512, 2) void conv_kernel(const u16* __restrict__ hb,
                                                      const u16* __restrict__ Wb,
                                                      float* __restrict__ P,
                                                      int koff, int kcnt) {
  const int L = blockIdx.x;            // 0..255
  const int o_t = L & 7;               // o-tile pinned per XCD (B L2 reuse, 4MB/XCD)
  const int rest = L >> 3;
  const int s_t = rest >> 2;           // 0..7
  const int z = rest & 3;              // i-quarter
  const int b = s_t >> 2, sloc = s_t & 3;
  const int s0l = sloc * 256;
  const int o0 = o_t * 128;
  const int ibase = z * 256;
  const int tid = threadIdx.x, lane = tid & 63, w = tid >> 6;
  const int wm = (w >> 2) & 1, wn = (w >> 1) & 1, ksid = w & 1;
  const int q15 = lane & 15, g = lane >> 4;
  __shared__ __align__(16) u16 Ad[2][288 * 64];   // 72 KB halo dbuf (rows: s0l-15 .. s0l+272)
  __shared__ __align__(16) u16 Bs[4][128 * 64];   // 64 KB shared ring-4
  const int rlo = (sloc == 0) ? 15 : 0;
  const int rhi = (sloc == 3) ? 271 : 286;
  if (sloc == 0)
    for (int i = tid; i < 15 * 64; i += 512) { Ad[0][i] = 0; Ad[1][i] = 0; }
  if (sloc == 3)
    for (int i = tid; i < 17 * 64; i += 512) { Ad[0][271 * 64 + i] = 0; Ad[1][271 * 64 + i] = 0; }
  auto stageA = [&](int buf, int i0) {
    for (int q = w; q < 36; q += 8) {            // 36 groups of 8 rows
      const int r = q * 8 + (lane >> 3);
      const int c = (lane & 7) ^ (r & 7);
      if (r >= rlo && r < rhi)
        GLOAD16(hb + (size_t)(b * SS + s0l - 15 + r) * DD + i0 + c * 8, &Ad[buf][q * 512]);
    }
  };
  auto stageB = [&](int slot, int k, int i0) {   // 128o x 64i, 2 gloads/wave
#pragma unroll
    for (int qq = 0; qq < 2; ++qq) {
      const int q = w * 2 + qq;
      const int r = q * 8 + (lane >> 3);         // 0..127 o-row
      const int c = (lane & 7) ^ (r & 7);
      GLOAD16(Wb + ((size_t)k * DD + o0 + r) * DD + i0 + c * 8, &Bs[slot][q * 512]);
    }
  };
  f32x4 acc[8][4];
#pragma unroll
  for (int i = 0; i < 8; ++i)
#pragma unroll
    for (int j = 0; j < 4; ++j) acc[i][j] = f32x4{0.f, 0.f, 0.f, 0.f};
  stageA(0, ibase);
  stageB(0, 0, ibase);
  stageB(1, 1, ibase);
  asm volatile("s_waitcnt vmcnt(0)" ::: "memory");
  __builtin_amdgcn_s_barrier();
  asm volatile("" ::: "memory");
  const int kx = ksid * 64;  // byte XOR selecting this wave's K=32 half (swizzle-compatible)
  int t = 0;
  for (int i0i = 0; i0i < 4; ++i0i) {
    const u16* Ab = Ad[i0i & 1];
    for (int k = 0; k < kcnt; ++k, ++t) {
      {  // prefetch B two rounds ahead
        int kn = k + 2, i0n = i0i;
        if (kn >= kcnt) { kn -= kcnt; ++i0n; }
        if (i0n < 4) stageB((t + 2) & 3, kn, ibase + i0n * 64);
      }
      // A-frag reads first (Ad barrier-protected at slice granularity)
      s16x8 af[8];
      const int rk0 = wm * 128 + q15 + koff + k;
#pragma unroll
      for (int mf = 0; mf < 8; ++mf) {
        const int rr = rk0 + mf * 16;
        const char* p = (const char*)Ab + rr * 128;
        af[mf] = *(const s16x8*)(p + (((g ^ (rr & 7)) * 16) ^ kx));
      }
      const bool last = (i0i == 3) && (k == kcnt - 1);
      const bool seclast = (i0i == 3) && (k == kcnt - 2);
      if (!last && !seclast) asm volatile("s_waitcnt vmcnt(4)" ::: "memory");
      else if (seclast)      asm volatile("s_waitcnt vmcnt(2)" ::: "memory");
      else                   asm volatile("s_waitcnt vmcnt(0)" ::: "memory");
      __builtin_amdgcn_s_barrier();                 // all waves' B(t) visible
      asm volatile("" ::: "memory");
      // A prefetch AFTER the wait+barrier so vmcnt(4) never forces a fresh load
      if (k == 5 && i0i < 3) stageA((i0i + 1) & 1, ibase + (i0i + 1) * 64);
      const u16* Bb = Bs[t & 3];
      s16x8 bfr[4];
#pragma unroll
      for (int nf = 0; nf < 4; ++nf) {
        const int rr = wn * 64 + nf * 16 + q15;
        const char* p = (const char*)Bb + rr * 128;
        bfr[nf] = *(const s16x8*)(p + (((g ^ (rr & 7)) * 16) ^ kx));
      }
      __builtin_amdgcn_s_setprio(1);
#pragma unroll
      for (int mf = 0; mf < 8; ++mf)
#pragma unroll
        for (int nf = 0; nf < 4; ++nf)
          acc[mf][nf] = MFMA16(af[mf], bfr[nf], acc[mf][nf]);
      __builtin_amdgcn_s_setprio(0);
      if (k == kcnt - 1 && i0i < 3) {       // slice boundary: A buffer swap
        asm volatile("s_waitcnt vmcnt(0)" ::: "memory");
        __syncthreads();
      }
    }
  }
  // ---- ks-pair reduction in 2 chunks (Bs reused as 64KB f32 scratch) ----
  __syncthreads();
  float* scr = (float*)(&Bs[0][0]) + (wm * 2 + wn) * 4096;
  float* Pz = P + (size_t)z * NTOK * DD;
#pragma unroll
  for (int half = 0; half < 2; ++half) {
    if (ksid == 1) {
#pragma unroll
      for (int m4 = 0; m4 < 4; ++m4)
#pragma unroll
        for (int nf = 0; nf < 4; ++nf) {
          const int col = nf * 16 + q15;
          *(f32x4*)&scr[col * 64 + ((m4 * 16 + g * 4) ^ ((col & 7) << 3))] = acc[half * 4 + m4][nf];
        }
    }
    __syncthreads();
    if (ksid == 0) {
#pragma unroll
      for (int m4 = 0; m4 < 4; ++m4) {
        f32x4 sum[4];
#pragma unroll
        for (int nf = 0; nf < 4; ++nf) {
          const int col = nf * 16 + q15;
          const f32x4 o = *(const f32x4*)&scr[col * 64 + ((m4 * 16 + g * 4) ^ ((col & 7) << 3))];
          sum[nf] = acc[half * 4 + m4][nf] + o;
        }
#pragma unroll
        for (int r = 0; r < 4; ++r) {
          const int srow = s0l + wm * 128 + (half * 4 + m4) * 16 + g * 4 + r;
          float* orow = Pz + (size_t)(b * SS + srow) * DD + o0 + wn * 64;
#pragma unroll
          for (int nf = 0; nf < 4; ++nf) {
            float v = sum[nf][r];
            if (koff) v += orow[nf * 16 + q15];   // pass-2 accumulates (f32, no bf16 loss)
            orow[nf * 16 + q15] = v;
          }
        }
      }
    }
    __syncthreads();
  }
}

// ---------------- combine: x1 = gelu(P0+P1+P2+P3+cb) + x ----------------
__global__ void combine_kernel(const float* __restrict__ P, const float* __restrict__ cb,
                               const float* __restrict__ x, float* __restrict__ x1) {
  const int idx = blockIdx.x * 256 + threadIdx.x;
  const size_t base = (size_t)idx * 4;
  const int col = (int)(base & (DD - 1));
  float4 p = *(const float4*)(P + base);
#pragma unroll
  for (int zz = 1; zz < 4; ++zz) {
    const float4 q = *(const float4*)(P + (size_t)zz * NTOK * DD + base);
    p.x += q.x; p.y += q.y; p.z += q.z; p.w += q.w;
  }
  const float4 xv = *(const float4*)(x + base);
  const float4 cbv = *(const float4*)(cb + col);
  float4 o;
  o.x = gelu_f(p.x + cbv.x) + xv.x;
  o.y = gelu_f(p.y + cbv.y) + xv.y;
  o.z = gelu_f(p.z + cbv.z) + xv.z;
  o.w = gelu_f(p.w + cbv.w) + xv.w;
  *(float4*)(x1 + base) = o;
}

// ---------------- qkv GEMM: qkvb[2048][3072] = hb @ inwb^T + in_b (bf16 out) ----------------
__global__ __launch_bounds__(256) void qkv_kernel(const u16* __restrict__ A, const u16* __restrict__ B,
                           const float* __restrict__ bias, u16* __restrict__ C) {
  const int n0 = blockIdx.x * 64, m0 = blockIdx.y * 128;
  const int tid = threadIdx.x, lane = tid & 63, w = tid >> 6;
  const int wm = w >> 1, wn = w & 1;
  __shared__ u16 As[2][128 * 64];
  __shared__ u16 Bs[2][64 * 64];
  f32x4 acc[4][2];
#pragma unroll
  for (int i = 0; i < 4; ++i)
#pragma unroll
    for (int j = 0; j < 2; ++j) acc[i][j] = f32x4{0.f, 0.f, 0.f, 0.f};
  auto stage = [&](int t, int buf) {
    const int k0 = t * 64;
#pragma unroll
    for (int q = 0; q < 4; ++q) {
      const int idx = w * 4 + q, r = idx * 8 + (lane >> 3), c = (lane & 7) ^ (r & 7);
      GLOAD16(A + (size_t)(m0 + r) * DD + k0 + c * 8, &As[buf][idx * 512]);
    }
#pragma unroll
    for (int q = 0; q < 2; ++q) {
      const int idx = w * 2 + q, r = idx * 8 + (lane >> 3), c = (lane & 7) ^ (r & 7);
      GLOAD16(B + (size_t)(n0 + r) * DD + k0 + c * 8, &Bs[buf][idx * 512]);
    }
  };
  stage(0, 0);
  asm volatile("s_waitcnt vmcnt(0)" ::: "memory");
  __syncthreads();
  const int T = DD / 64;
  for (int t = 0; t < T; ++t) {
    if (t + 1 < T) stage(t + 1, (t + 1) & 1);
    const u16* Ab = As[t & 1];
    const u16* Bb = Bs[t & 1];
    const int xb = (((lane >> 4) ^ (lane & 7)) * 16);
    s16x8 af[4][2], bfr[2][2];
#pragma unroll
    for (int mf = 0; mf < 4; ++mf) {
      const char* p = (const char*)Ab + (wm * 64 + mf * 16 + (lane & 15)) * 128;
      af[mf][0] = *(const s16x8*)(p + xb);
      af[mf][1] = *(const s16x8*)(p + (xb ^ 64));
    }
#pragma unroll
    for (int nf = 0; nf < 2; ++nf) {
      const char* p = (const char*)Bb + (wn * 32 + nf * 16 + (lane & 15)) * 128;
      bfr[nf][0] = *(const s16x8*)(p + xb);
      bfr[nf][1] = *(const s16x8*)(p + (xb ^ 64));
    }
#pragma unroll
    for (int ks = 0; ks < 2; ++ks)
#pragma unroll
      for (int mf = 0; mf < 4; ++mf)
#pragma unroll
        for (int nf = 0; nf < 2; ++nf)
          acc[mf][nf] = MFMA16(af[mf][ks], bfr[nf][ks], acc[mf][nf]);
    asm volatile("s_waitcnt vmcnt(0)" ::: "memory");
    __syncthreads();
  }
#pragma unroll
  for (int mf = 0; mf < 4; ++mf)
#pragma unroll
    for (int rr = 0; rr < 4; ++rr) {
      const int row = m0 + wm * 64 + mf * 16 + (lane >> 4) * 4 + rr;
#pragma unroll
      for (int nf = 0; nf < 2; ++nf) {
        const int col = n0 + wn * 32 + nf * 16 + (lane & 15);
        C[(size_t)row * D3 + col] = f2bf(acc[mf][nf][rr] + bias[col]);
      }
    }
}

// ---------------- out proj: x2 = ctxb @ outwb^T + out_b + x1 (f32 + bf16 out) ----------------
__global__ __launch_bounds__(256) void out_kernel(const u16* __restrict__ A, const u16* __restrict__ B,
                           const float* __restrict__ bias, const float* __restrict__ resid,
                           float* __restrict__ C, u16* __restrict__ Cb) {
  const int n0 = blockIdx.x * 64, m0 = blockIdx.y * 128;
  const int tid = threadIdx.x, lane = tid & 63, w = tid >> 6;
  const int wm = w >> 1, wn = w & 1;
  __shared__ u16 As[2][128 * 64];
  __shared__ u16 Bs[2][64 * 64];
  f32x4 acc[4][2];
#pragma unroll
  for (int i = 0; i < 4; ++i)
#pragma unroll
    for (int j = 0; j < 2; ++j) acc[i][j] = f32x4{0.f, 0.f, 0.f, 0.f};
  auto stage = [&](int t, int buf) {
    const int k0 = t * 64;
#pragma unroll
    for (int q = 0; q < 4; ++q) {
      const int idx = w * 4 + q, r = idx * 8 + (lane >> 3), c = (lane & 7) ^ (r & 7);
      GLOAD16(A + (size_t)(m0 + r) * DD + k0 + c * 8, &As[buf][idx * 512]);
    }
#pragma unroll
    for (int q = 0; q < 2; ++q) {
      const int idx = w * 2 + q, r = idx * 8 + (lane >> 3), c = (lane & 7) ^ (r & 7);
      GLOAD16(B + (size_t)(n0 + r) * DD + k0 + c * 8, &Bs[buf][idx * 512]);
    }
  };
  stage(0, 0);
  asm volatile("s_waitcnt vmcnt(0)" ::: "memory");
  __syncthreads();
  const int T = DD / 64;
  for (int t = 0; t < T; ++t) {
    if (t + 1 < T) stage(t + 1, (t + 1) & 1);
    const u16* Ab = As[t & 1];
    const u16* Bb = Bs[t & 1];
    const int xb = (((lane >> 4) ^ (lane & 7)) * 16);
    s16x8 af[4][2], bfr[2][2];
#pragma unroll
    for (int mf = 0; mf < 4; ++mf) {
      const char* p = (const char*)Ab + (wm * 64 + mf * 16 + (lane & 15)) * 128;
      af[mf][0] = *(const s16x8*)(p + xb);
      af[mf][1] = *(const s16x8*)(p + (xb ^ 64));
    }
#pragma unroll
    for (int nf = 0; nf < 2; ++nf) {
      const char* p = (const char*)Bb + (wn * 32 + nf * 16 + (lane & 15)) * 128;
      bfr[nf][0] = *(const s16x8*)(p + xb);
      bfr[nf][1] = *(const s16x8*)(p + (xb ^ 64));
    }
#pragma unroll
    for (int ks = 0; ks < 2; ++ks)
#pragma unroll
      for (int mf = 0; mf < 4; ++mf)
#pragma unroll
        for (int nf = 0; nf < 2; ++nf)
          acc[mf][nf] = MFMA16(af[mf][ks], bfr[nf][ks], acc[mf][nf]);
    asm volatile("s_waitcnt vmcnt(0)" ::: "memory");
    __syncthreads();
  }
#pragma unroll
  for (int mf = 0; mf < 4; ++mf)
#pragma unroll
    for (int rr = 0; rr < 4; ++rr) {
      const int row = m0 + wm * 64 + mf * 16 + (lane >> 4) * 4 + rr;
#pragma unroll
      for (int nf = 0; nf < 2; ++nf) {
        const int col = n0 + wn * 32 + nf * 16 + (lane & 15);
        const float v = acc[mf][nf][rr] + bias[col] + resid[(size_t)row * DD + col];
        C[(size_t)row * DD + col] = v;
        Cb[(size_t)row * DD + col] = f2bf(v);
      }
    }
}

// ---------------- MFMA flash attention: 128 q x (b,h) per block, 8 waves x 16 q ----------------
__global__ __launch_bounds__(512) void attn_kernel(const u16* __restrict__ qkv,
                                                   const u16* __restrict__ Vt,
                                                   u16* __restrict__ ctx) {
  const int q0 = blockIdx.x * 128, h = blockIdx.y, b = blockIdx.z;
  const int tid = threadIdx.x, lane = tid & 63, w = tid >> 6;
  const int q15 = lane & 15, g = lane >> 4, l7 = lane & 7;
  __shared__ u16 Q_lds[128 * 64];
  __shared__ u16 K_lds[2][64 * 64];
  __shared__ u16 V_lds[2][64 * 64];
  __shared__ u16 P_lds[8][16 * 72];
  __shared__ float s_lds[8][16];

#pragma unroll
  for (int q2 = 0; q2 < 2; ++q2) {
    const int idx = w * 2 + q2;
    const int r = idx * 8 + (lane >> 3);
    const int c = l7 ^ (r & 7);
    GLOAD16(qkv + (size_t)(b * SS + q0 + r) * D3 + h * HDIM + c * 8, &Q_lds[idx * 512]);
  }
  auto stageK = [&](int buf, int kt) {
    const int r = w * 8 + (lane >> 3);
    const int c = l7 ^ (r & 7);
    GLOAD16(qkv + (size_t)(b * SS + kt * 64 + r) * D3 + DD + h * HDIM + c * 8,
            &K_lds[buf][w * 512]);
  };
  auto stageV = [&](int buf, int kt) {
    const int r = w * 8 + (lane >> 3);
    const int c = l7 ^ (r & 7);
    GLOAD16(Vt + ((size_t)(b * HH + h) * HDIM + r) * SS + kt * 64 + c * 8,
            &V_lds[buf][w * 512]);
  };
  stageK(0, 0);
  stageV(0, 0);
  asm volatile("s_waitcnt vmcnt(0)" ::: "memory");
  __syncthreads();
  s16x8 bq[2];
#pragma unroll
  for (int ks = 0; ks < 2; ++ks)
    bq[ks] = *(const s16x8*)((const char*)Q_lds + (w * 16 + q15) * 128 + ((4 * ks + g) ^ l7) * 16);
  f32x4 oacc[4];
#pragma unroll
  for (int nf = 0; nf < 4; ++nf) oacc[nf] = f32x4{0.f, 0.f, 0.f, 0.f};
  float mrun = -3.0e38f, lrun = 0.0f;
  int buf = 0;
  for (int kt = 0; kt < 16; ++kt) {
    if (kt < 15) { stageK(buf ^ 1, kt + 1); stageV(buf ^ 1, kt + 1); }
    f32x4 st[4];
#pragma unroll
    for (int mf = 0; mf < 4; ++mf) st[mf] = f32x4{0.f, 0.f, 0.f, 0.f};
#pragma unroll
    for (int ks = 0; ks < 2; ++ks) {
#pragma unroll
      for (int mf = 0; mf < 4; ++mf) {
        const s16x8 ka = *(const s16x8*)((const char*)K_lds[buf] + (mf * 16 + q15) * 128 +
                                         ((4 * ks + g) ^ l7) * 16);
        st[mf] = MFMA16(ka, bq[ks], st[mf]);
      }
    }
    float t0[4][4];
    float cmax = -3.0e38f;
#pragma unroll
    for (int mf = 0; mf < 4; ++mf)
#pragma unroll
      for (int r = 0; r < 4; ++r) {
        const float v = st[mf][r] * 0.125f;
        t0[mf][r] = v;
        cmax = fmaxf(cmax, v);
      }
    cmax = fmaxf(cmax, __shfl_xor(cmax, 16));
    cmax = fmaxf(cmax, __shfl_xor(cmax, 32));
    const float mnew = fmaxf(mrun, cmax);
    const float scf = __expf(mrun - mnew);
    float psum = 0.f;
#pragma unroll
    for (int mf = 0; mf < 4; ++mf)
#pragma unroll
      for (int r = 0; r < 4; ++r) {
        const float p = __expf(t0[mf][r] - mnew);
        t0[mf][r] = p;
        psum += p;
      }
    psum += __shfl_xor(psum, 16);
    psum += __shfl_xor(psum, 32);
    lrun = lrun * scf + psum;
    mrun = mnew;
    s_lds[w][q15] = scf;
    u16* pw = &P_lds[w][0];
#pragma unroll
    for (int mf = 0; mf < 4; ++mf) {
      u32x2 pk;
      pk[0] = (unsigned)f2bf(t0[mf][0]) | ((unsigned)f2bf(t0[mf][1]) << 16);
      pk[1] = (unsigned)f2bf(t0[mf][2]) | ((unsigned)f2bf(t0[mf][3]) << 16);
      *(u32x2*)(pw + q15 * 72 + mf * 16 + g * 4) = pk;
    }
    asm volatile("s_waitcnt lgkmcnt(0)" ::: "memory");
    const f32x4 scv = *(const f32x4*)&s_lds[w][g * 4];
#pragma unroll
    for (int nf = 0; nf < 4; ++nf)
#pragma unroll
      for (int r = 0; r < 4; ++r) oacc[nf][r] *= scv[r];
#pragma unroll
    for (int ks = 0; ks < 2; ++ks) {
      const s16x8 pa = *(const s16x8*)(pw + q15 * 72 + ks * 32 + g * 8);
#pragma unroll
      for (int nf = 0; nf < 4; ++nf) {
        const s16x8 bv = *(const s16x8*)((const char*)V_lds[buf] + (nf * 16 + q15) * 128 +
                                         ((4 * ks + g) ^ l7) * 16);
        oacc[nf] = MFMA16(pa, bv, oacc[nf]);
      }
    }
    asm volatile("s_waitcnt vmcnt(0)" ::: "memory");
    __syncthreads();
    buf ^= 1;
  }
  const float linv = 1.0f / lrun;
  s_lds[w][q15] = linv;
  asm volatile("s_waitcnt lgkmcnt(0)" ::: "memory");
  const f32x4 lv = *(const f32x4*)&s_lds[w][g * 4];
#pragma unroll
  for (int nf = 0; nf < 4; ++nf)
#pragma unroll
    for (int r = 0; r < 4; ++r) {
      const int qg = q0 + w * 16 + g * 4 + r;
      ctx[(size_t)(b * SS + qg) * DD + h * HDIM + nf * 16 + q15] = f2bf(oacc[nf][r] * lv[r]);
    }
}

// ---------------- MoE routing ----------------
__global__ void zero_counts_kernel(int* c) { if (threadIdx.x < GG) c[threadIdx.x] = 0; }

__global__ void gather_kernel(const int* __restrict__ gid, int* __restrict__ counts,
                              int* __restrict__ gather) {
  const int n = blockIdx.x * 256 + threadIdx.x;
  if (n < NTOK) {
    const int g = gid[n];
    const int slot = atomicAdd(&counts[g], 1);
    gather[g * NTOK + slot] = n;
  }
}

// ---------------- MoE GEMM1: h1[e][tok] = gelu(x2b[tok] @ w1t[g,e]^T + b1) ----------------
__global__ __launch_bounds__(256) void moe1_kernel(const u16* __restrict__ x2b, const u16* __restrict__ w1t,
                            const float* __restrict__ e_b1, const int* __restrict__ gat,
                            const int* __restrict__ cnts, u16* __restrict__ h1) {
  const int ge = blockIdx.z, g = ge >> 1, e = ge & 1;
  const int cnt = cnts[g];
  const int m0 = blockIdx.x * 128;
  if (m0 >= cnt) return;
  const int n0 = blockIdx.y * 64;
  const int* gl = gat + g * NTOK;
  const u16* B = w1t + (size_t)ge * HIDN * DD;  // [HID][D]
  const int tid = threadIdx.x, lane = tid & 63, w = tid >> 6;
  const int wm = w >> 1, wn = w & 1;
  __shared__ u16 As[2][128 * 64];
  __shared__ u16 Bs[2][64 * 64];
  f32x4 acc[4][2];
#pragma unroll
  for (int i = 0; i < 4; ++i)
#pragma unroll
    for (int j = 0; j < 2; ++j) acc[i][j] = f32x4{0.f, 0.f, 0.f, 0.f};
  auto stage = [&](int t, int buf) {
    const int k0 = t * 64;
#pragma unroll
    for (int q = 0; q < 4; ++q) {
      const int idx = w * 4 + q, r = idx * 8 + (lane >> 3), c = (lane & 7) ^ (r & 7);
      int rg = m0 + r; if (rg > cnt - 1) rg = cnt - 1;
      const int tok = gl[rg];
      GLOAD16(x2b + (size_t)tok * DD + k0 + c * 8, &As[buf][idx * 512]);
    }
#pragma unroll
    for (int q = 0; q < 2; ++q) {
      const int idx = w * 2 + q, r = idx * 8 + (lane >> 3), c = (lane & 7) ^ (r & 7);
      GLOAD16(B + (size_t)(n0 + r) * DD + k0 + c * 8, &Bs[buf][idx * 512]);
    }
  };
  stage(0, 0);
  asm volatile("s_waitcnt vmcnt(0)" ::: "memory");
  __syncthreads();
  const int T = DD / 64;
  for (int t = 0; t < T; ++t) {
    if (t + 1 < T) stage(t + 1, (t + 1) & 1);
    const u16* Ab = As[t & 1];
    const u16* Bb = Bs[t & 1];
    const int xb = (((lane >> 4) ^ (lane & 7)) * 16);
    s16x8 af[4][2], bfr[2][2];
#pragma unroll
    for (int mf = 0; mf < 4; ++mf) {
      const char* p = (const char*)Ab + (wm * 64 + mf * 16 + (lane & 15)) * 128;
      af[mf][0] = *(const s16x8*)(p + xb);
      af[mf][1] = *(const s16x8*)(p + (xb ^ 64));
    }
#pragma unroll
    for (int nf = 0; nf < 2; ++nf) {
      const char* p = (const char*)Bb + (wn * 32 + nf * 16 + (lane & 15)) * 128;
      bfr[nf][0] = *(const s16x8*)(p + xb);
      bfr[nf][1] = *(const s16x8*)(p + (xb ^ 64));
    }
#pragma unroll
    for (int ks = 0; ks < 2; ++ks)
#pragma unroll
      for (int mf = 0; mf < 4; ++mf)
#pragma unroll
        for (int nf = 0; nf < 2; ++nf)
          acc[mf][nf] = MFMA16(af[mf][ks], bfr[nf][ks], acc[mf][nf]);
    asm volatile("s_waitcnt vmcnt(0)" ::: "memory");
    __syncthreads();
  }
  const float* b1 = e_b1 + (size_t)ge * HIDN;
#pragma unroll
  for (int mf = 0; mf < 4; ++mf)
#pragma unroll
    for (int rr = 0; rr < 4; ++rr) {
      const int rowg = m0 + wm * 64 + mf * 16 + (lane >> 4) * 4 + rr;
      if (rowg < cnt) {
        const int tok = gl[rowg];
        u16* orow = h1 + ((size_t)e * NTOK + tok) * HIDN;
#pragma unroll
        for (int nf = 0; nf < 2; ++nf) {
          const int col = n0 + wn * 32 + nf * 16 + (lane & 15);
          orow[col] = f2bf(gelu_f(acc[mf][nf][rr] + b1[col]));
        }
      }
    }
}

// ---------------- MoE GEMM2: out[tok] = 0.5*sum_e h1[e][tok] @ w2t[g,e]^T + 0.5*(b2_0+b2_1) + x2 ----------------
__global__ __launch_bounds__(256) void moe2_kernel(const u16* __restrict__ h1, const u16* __restrict__ w2t,
                            const float* __restrict__ e_b2, const int* __restrict__ gat,
                            const int* __restrict__ cnts, const float* __restrict__ x2,
                            float* __restrict__ outp) {
  const int g = blockIdx.z;
  const int cnt = cnts[g];
  const int m0 = blockIdx.x * 128;
  if (m0 >= cnt) return;
  const int n0 = blockIdx.y * 64;
  const int* gl = gat + g * NTOK;
  const int tid = threadIdx.x, lane = tid & 63, w = tid >> 6;
  const int wm = w >> 1, wn = w & 1;
  __shared__ u16 As[2][128 * 64];
  __shared__ u16 Bs[2][64 * 64];
  f32x4 acc[4][2];
#pragma unroll
  for (int i = 0; i < 4; ++i)
#pragma unroll
    for (int j = 0; j < 2; ++j) acc[i][j] = f32x4{0.f, 0.f, 0.f, 0.f};
  auto stage = [&](int t, int buf) {
    const int e = t >> 5;
    const int k0 = (t & 31) * 64;
#pragma unroll
    for (int q = 0; q < 4; ++q) {
      const int idx = w * 4 + q, r = idx * 8 + (lane >> 3), c = (lane & 7) ^ (r & 7);
      int rg = m0 + r; if (rg > cnt - 1) rg = cnt - 1;
      const int tok = gl[rg];
      GLOAD16(h1 + ((size_t)e * NTOK + tok) * HIDN + k0 + c * 8, &As[buf][idx * 512]);
    }
#pragma unroll
    for (int q = 0; q < 2; ++q) {
      const int idx = w * 2 + q, r = idx * 8 + (lane >> 3), c = (lane & 7) ^ (r & 7);
      GLOAD16(w2t + ((size_t)(g * EE + e) * DD + n0 + r) * HIDN + k0 + c * 8, &Bs[buf][idx * 512]);
    }
  };
  stage(0, 0);
  asm volatile("s_waitcnt vmcnt(0)" ::: "memory");
  __syncthreads();
  const int T = 64;
  for (int t = 0; t < T; ++t) {
    if (t + 1 < T) stage(t + 1, (t + 1) & 1);
    const u16* Ab = As[t & 1];
    const u16* Bb = Bs[t & 1];
    const int xb = (((lane >> 4) ^ (lane & 7)) * 16);
    s16x8 af[4][2], bfr[2][2];
#pragma unroll
    for (int mf = 0; mf < 4; ++mf) {
      const char* p = (const char*)Ab + (wm * 64 + mf * 16 + (lane & 15)) * 128;
      af[mf][0] = *(const s16x8*)(p + xb);
      af[mf][1] = *(const s16x8*)(p + (xb ^ 64));
    }
#pragma unroll
    for (int nf = 0; nf < 2; ++nf) {
      const char* p = (const char*)Bb + (wn * 32 + nf * 16 + (lane & 15)) * 128;
      bfr[nf][0] = *(const s16x8*)(p + xb);
      bfr[nf][1] = *(const s16x8*)(p + (xb ^ 64));
    }
#pragma unroll
    for (int ks = 0; ks < 2; ++ks)
#pragma unroll
      for (int mf = 0; mf < 4; ++mf)
#pragma unroll
        for (int nf = 0; nf < 2; ++nf)
          acc[mf][nf] = MFMA16(af[mf][ks], bfr[nf][ks], acc[mf][nf]);
    asm volatile("s_waitcnt vmcnt(0)" ::: "memory");
    __syncthreads();
  }
  const float* b20 = e_b2 + (size_t)(g * EE + 0) * DD;
  const float* b21 = e_b2 + (size_t)(g * EE + 1) * DD;
#pragma unroll
  for (int mf = 0; mf < 4; ++mf)
#pragma unroll
    for (int rr = 0; rr < 4; ++rr) {
      const int rowg = m0 + wm * 64 + mf * 16 + (lane >> 4) * 4 + rr;
      if (rowg < cnt) {
        const int tok = gl[rowg];
#pragma unroll
        for (int nf = 0; nf < 2; ++nf) {
          const int col = n0 + wn * 32 + nf * 16 + (lane & 15);
          outp[(size_t)tok * DD + col] =
              0.5f * acc[mf][nf][rr] + 0.5f * (b20[col] + b21[col]) + x2[(size_t)tok * DD + col];
        }
      }
    }
}

extern "C" void kernel_launch(void* const* d_in, const int* in_sizes, int n_in,
                              void* d_out, int out_size, void* d_ws, size_t ws_size,
                              hipStream_t stream) {
  (void)in_sizes; (void)n_in; (void)out_size; (void)ws_size;
  const float* x      = (const float*)d_in[0];
  const int*   gid    = (const int*)d_in[1];
  const float* cn_g   = (const float*)d_in[2];
  const float* cn_b   = (const float*)d_in[3];
  const float* conv_w = (const float*)d_in[4];
  const float* conv_b = (const float*)d_in[5];
  const float* an_g   = (const float*)d_in[6];
  const float* an_b   = (const float*)d_in[7];
  const float* in_w   = (const float*)d_in[8];
  const float* in_b   = (const float*)d_in[9];
  const float* out_w  = (const float*)d_in[10];
  const float* out_b  = (const float*)d_in[11];
  const float* e_w1   = (const float*)d_in[12];
  const float* e_b1   = (const float*)d_in[13];
  const float* e_w2   = (const float*)d_in[14];
  const float* e_b2   = (const float*)d_in[15];
  float* outp = (float*)d_out;

  // ---- workspace map (high-water 74MB + 32KB, unchanged) ----
  // conv phase:  hb 0..4 | Pc f32 x4 4..36 | Wb' 36..68 (per-pass taps)
  // post-conv:   x1 36..44 (Wb' dead) | inwb 44..50 | qkvb 50..62 | Vt 62..66 | outwb 44..46
  //              x2 4..12 (Pc dead) | x2b 12..16
  // MoE phase:   wgt 16..48 | h1 48..64 | gat/cnts @74M
  char* wsp = (char*)d_ws;
  u16*   hb    = (u16*)(wsp);                         // 0..4M  (ln out; ctxb reuse)
  float* Pc    = (float*)(wsp + (4ull << 20));        // 4..36M (conv f32 partials x4)
  u16*   Wb    = (u16*)(wsp + (36ull << 20));         // 36..68M (conv phase only)
  float* x1    = (float*)(wsp + (36ull << 20));       // 36..44M (combine out, after conv)
  u16*   inwb  = (u16*)(wsp + (44ull << 20));         // 44..50M (qkv phase)
  u16*   qkvb  = (u16*)(wsp + (50ull << 20));         // 50..62M (qkv->attn)
  u16*   Vt    = (u16*)(wsp + (62ull << 20));         // 62..66M (attn phase)
  u16*   outwb = (u16*)(wsp + (44ull << 20));         // 44..46M (out phase, after qkv)
  u16*   ctxb  = hb;                                  // 0..4M  (after qkv)
  float* x2    = (float*)(wsp + (4ull << 20));        // 4..12M  (after combine, Pc dead)
  u16*   x2b   = (u16*)(wsp + (12ull << 20));         // 12..16M
  u16*   wgt   = (u16*)(wsp + (16ull << 20));         // 16..48M (w1t, then w2t; MoE phase)
  u16*   h1    = (u16*)(wsp + (48ull << 20));         // 48..64M (MoE phase)
  int*   gat   = (int*)(wsp + (74ull << 20));         // 32KB
  int*   cnts  = (int*)(wsp + (74ull << 20) + (size_t)GG * NTOK * 4);

  // ---- conv block (two tap-passes: 0..15 then 16..30, P accumulates in f32) ----
  ln_kernel<<<NTOK, 256, 0, stream>>>(x, cn_g, cn_b, hb);
  prep_convw<<<1024, 256, 0, stream>>>(conv_w, Wb, 0, 16);
  conv_kernel<<<256, 512, 0, stream>>>(hb, Wb, Pc, 0, 16);
  prep_convw<<<1024, 256, 0, stream>>>(conv_w, Wb, 16, 15);
  conv_kernel<<<256, 512, 0, stream>>>(hb, Wb, Pc, 16, 15);
  combine_kernel<<<NTOK * DD / 1024, 256, 0, stream>>>(Pc, conv_b, x, x1);
  // ---- attention block ----
  ln_kernel<<<NTOK, 256, 0, stream>>>(x1, an_g, an_b, hb);
  cvt_kernel<<<3072, 256, 0, stream>>>(in_w, inwb, 3 * DD * DD / 4);
  qkv_kernel<<<dim3(D3 / 64, NTOK / 128), 256, 0, stream>>>(hb, inwb, in_b, qkvb);
  vtr_kernel<<<dim3(SS / 32, HDIM / 32, BB * HH), 256, 0, stream>>>(qkvb, Vt);
  attn_kernel<<<dim3(SS / 128, HH, BB), 512, 0, stream>>>(qkvb, Vt, ctxb);
  cvt_kernel<<<1024, 256, 0, stream>>>(out_w, outwb, DD * DD / 4);
  out_kernel<<<dim3(DD / 64, NTOK / 128), 256, 0, stream>>>(ctxb, outwb, out_b, x1, x2, x2b);
  // ---- MoE ----
  zero_counts_kernel<<<1, 64, 0, stream>>>(cnts);
  gather_kernel<<<NTOK / 256, 256, 0, stream>>>(gid, cnts, gat);
  tr_kernel<<<dim3(HIDN / 32, DD / 32, GG * EE), 256, 0, stream>>>(e_w1, wgt, DD, HIDN);
  moe1_kernel<<<dim3(NTOK / 128, HIDN / 64, GG * EE), 256, 0, stream>>>(x2b, wgt, e_b1, gat, cnts, h1);
  tr_kernel<<<dim3(DD / 32, HIDN / 32, GG * EE), 256, 0, stream>>>(e_w2, wgt, HIDN, DD);
  moe2_kernel<<<dim3(NTOK / 128, DD / 64, GG), 256, 0, stream>>>(h1, wgt, e_b2, gat, cnts, x2, outp);
}

// Round 3
// 684.115 us; speedup vs baseline: 1.0445x; 1.0445x over previous
//
#include <hip/hip_runtime.h>
#include <hip/hip_bf16.h>
#include <math.h>

#define BB 2
#define SS 1024
#define DD 1024
#define HH 16
#define HDIM 64
#define KK 31
#define GG 4
#define EE 2
#define HIDN 2048
#define NTOK (BB*SS)
#define D3 (3*DD)

typedef unsigned short u16;
typedef __attribute__((ext_vector_type(8))) short s16x8;
typedef __attribute__((ext_vector_type(8))) unsigned short u16x8;
typedef __attribute__((ext_vector_type(4))) unsigned short u16x4;
typedef __attribute__((ext_vector_type(4))) float f32x4;
typedef __attribute__((ext_vector_type(2))) unsigned int u32x2;

__device__ __forceinline__ float gelu_f(float x) {
  return 0.5f * x * (1.0f + erff(x * 0.7071067811865475f));
}
__device__ __forceinline__ u16 f2bf(float f) {
  unsigned u = __builtin_bit_cast(unsigned, f);
  u = (u + 0x7fffu + ((u >> 16) & 1u)) >> 16;
  return (u16)u;
}
__device__ __forceinline__ float bf2f(u16 u) {
  return __builtin_bit_cast(float, ((unsigned)u) << 16);
}
__device__ __forceinline__ f32x4 MFMA16(s16x8 a, s16x8 b, f32x4 c) {
  return __builtin_amdgcn_mfma_f32_16x16x32_bf16(a, b, c, 0, 0, 0);
}
#define GLOAD16(gp, lp) __builtin_amdgcn_global_load_lds( \
    (const __attribute__((address_space(1))) void*)(gp),  \
    (__attribute__((address_space(3))) void*)(lp), 16, 0, 0)

// ---------------- LayerNorm: fp32 in -> bf16 out, one block per row ----------------
__global__ void ln_kernel(const float* __restrict__ x, const float* __restrict__ g,
                          const float* __restrict__ b, u16* __restrict__ out) {
  const int row = blockIdx.x;
  const int tid = threadIdx.x;
  __shared__ float red[4];
  const float4 v = reinterpret_cast<const float4*>(x + (size_t)row * DD)[tid];
  float s = v.x + v.y + v.z + v.w;
  s += __shfl_down(s, 32); s += __shfl_down(s, 16); s += __shfl_down(s, 8);
  s += __shfl_down(s, 4);  s += __shfl_down(s, 2);  s += __shfl_down(s, 1);
  if ((tid & 63) == 0) red[tid >> 6] = s;
  __syncthreads();
  const float mean = (red[0] + red[1] + red[2] + red[3]) * (1.0f / DD);
  __syncthreads();
  const float4 d = make_float4(v.x - mean, v.y - mean, v.z - mean, v.w - mean);
  float sq = d.x*d.x + d.y*d.y + d.z*d.z + d.w*d.w;
  sq += __shfl_down(sq, 32); sq += __shfl_down(sq, 16); sq += __shfl_down(sq, 8);
  sq += __shfl_down(sq, 4);  sq += __shfl_down(sq, 2);  sq += __shfl_down(sq, 1);
  if ((tid & 63) == 0) red[tid >> 6] = sq;
  __syncthreads();
  const float var = (red[0] + red[1] + red[2] + red[3]) * (1.0f / DD);
  const float rstd = rsqrtf(var + 1e-5f);
  const float4 gv = reinterpret_cast<const float4*>(g)[tid];
  const float4 bv = reinterpret_cast<const float4*>(b)[tid];
  u16x4 o;
  o[0] = f2bf(d.x * rstd * gv.x + bv.x);
  o[1] = f2bf(d.y * rstd * gv.y + bv.y);
  o[2] = f2bf(d.z * rstd * gv.z + bv.z);
  o[3] = f2bf(d.w * rstd * gv.w + bv.w);
  *reinterpret_cast<u16x4*>(out + (size_t)row * DD + tid * 4) = o;
}

// ---------------- conv weight reorder: conv_w[o][i][k] f32 -> Wb[k][o][i] bf16 ----------------
__global__ void prep_convw(const float* __restrict__ cw, u16* __restrict__ Wb) {
  const int o = blockIdx.x;
#pragma unroll
  for (int rep = 0; rep < 4; ++rep) {
    const int i = rep * 256 + threadIdx.x;
    const float* src = cw + ((size_t)o * DD + i) * KK;
    float wv[KK];
#pragma unroll
    for (int k = 0; k < KK; ++k) wv[k] = src[k];
#pragma unroll
    for (int k = 0; k < KK; ++k)
      Wb[((size_t)k * DD + o) * DD + i] = f2bf(wv[k]);
  }
}

// ---------------- plain f32 -> bf16 convert ----------------
__global__ void cvt_kernel(const float* __restrict__ in, u16* __restrict__ outp, int n4) {
  const int i = blockIdx.x * 256 + threadIdx.x;
  if (i < n4) {
    const float4 v = reinterpret_cast<const float4*>(in)[i];
    u16x4 o; o[0] = f2bf(v.x); o[1] = f2bf(v.y); o[2] = f2bf(v.z); o[3] = f2bf(v.w);
    reinterpret_cast<u16x4*>(outp)[i] = o;
  }
}

// ---------------- transpose-convert: src[z][R][C] f32 -> dst[z][C][R] bf16 ----------------
__global__ void tr_kernel(const float* __restrict__ src, u16* __restrict__ dst, int R, int C) {
  __shared__ float tile[32][33];
  const int c0 = blockIdx.x * 32, r0 = blockIdx.y * 32;
  const size_t base = (size_t)blockIdx.z * R * C;
  const int tx = threadIdx.x & 31, ty = threadIdx.x >> 5;  // ty 0..7
#pragma unroll
  for (int i = 0; i < 4; ++i)
    tile[ty + i * 8][tx] = src[base + (size_t)(r0 + ty + i * 8) * C + c0 + tx];
  __syncthreads();
#pragma unroll
  for (int i = 0; i < 4; ++i)
    dst[base + (size_t)(c0 + ty + i * 8) * R + r0 + tx] = f2bf(tile[tx][ty + i * 8]);
}

// ---------------- V transpose: qkvb V-part -> Vt[b][h][d][k] bf16 ----------------
__global__ void vtr_kernel(const u16* __restrict__ qkvb, u16* __restrict__ Vt) {
  __shared__ u16 tile[32][40];
  const int k0 = blockIdx.x * 32, d0 = blockIdx.y * 32, bh = blockIdx.z;
  const int b = bh >> 4, h = bh & 15;
  const int tx = threadIdx.x & 31, ty = threadIdx.x >> 5;  // ty 0..7
#pragma unroll
  for (int i = 0; i < 4; ++i)
    tile[ty + i * 8][tx] =
        qkvb[(size_t)(b * SS + k0 + ty + i * 8) * D3 + 2 * DD + h * HDIM + d0 + tx];
  __syncthreads();
#pragma unroll
  for (int i = 0; i < 4; ++i)
    Vt[((size_t)(b * HH + h) * HDIM + d0 + ty + i * 8) * SS + k0 + tx] = tile[tx][ty + i * 8];
}

// ---------------- conv via MFMA v2 (measured 208us): 8 waves, shared ring-4 B staging ----------------
// block tile 128s x 128o, 8 waves = 2(s) x 2(o) x 2(ks); wave tile 64s x 64o, half-K each.
// B staging BLOCK-SHARED ring-4 (deduped, 2 gloads/wave/round), one raw s_barrier/round,
// counted vmcnt(4) (tail 2->0) so loads span barriers. LDS 104KB -> 2 waves/SIMD.
__global__ __launch_bounds__(512) void conv_kernel(const u16* __restrict__ hb,
                                                   const u16* __restrict__ Wb,
                                                   u16* __restrict__ P) {
  const int L = blockIdx.x;            // 0..255
  const int o_t = L & 7;               // o-tile pinned per XCD (B L2 reuse)
  const int rest = L >> 3;
  const int s_t = rest >> 1;           // 0..15
  const int z = rest & 1;              // i-half
  const int b = s_t >> 3, sloc = s_t & 7;
  const int s0l = sloc * 128;
  const int o0 = o_t * 128;
  const int ibase = z * 512;
  const int tid = threadIdx.x, lane = tid & 63, w = tid >> 6;
  const int wm = (w >> 2) & 1, wn = (w >> 1) & 1, ksid = w & 1;
  const int q15 = lane & 15, g = lane >> 4;
  __shared__ __align__(16) u16 Ad[2][160 * 64];   // 40 KB, dbuf over i-slices
  __shared__ __align__(16) u16 Bs[4][128 * 64];   // 64 KB, shared ring-4
  const int rlo = (sloc == 0) ? 15 : 0;
  const int rhi = (sloc == 7) ? 143 : 158;
  if (sloc == 0)
    for (int i = tid; i < 15 * 64; i += 512) { Ad[0][i] = 0; Ad[1][i] = 0; }
  if (sloc == 7)
    for (int i = tid; i < 17 * 64; i += 512) { Ad[0][143 * 64 + i] = 0; Ad[1][143 * 64 + i] = 0; }
  auto stageA = [&](int buf, int i0) {
    for (int q = w; q < 20; q += 8) {          // waves 0-3: 3 groups, 4-7: 2 groups
      const int r = q * 8 + (lane >> 3);
      const int c = (lane & 7) ^ (r & 7);
      if (r >= rlo && r < rhi)
        GLOAD16(hb + (size_t)(b * SS + s0l - 15 + r) * DD + i0 + c * 8, &Ad[buf][q * 512]);
    }
  };
  auto stageB = [&](int slot, int k, int i0) {  // 128o x 64i, 2 gloads/wave
#pragma unroll
    for (int qq = 0; qq < 2; ++qq) {
      const int q = w * 2 + qq;
      const int r = q * 8 + (lane >> 3);        // 0..127 o-row
      const int c = (lane & 7) ^ (r & 7);
      GLOAD16(Wb + ((size_t)k * DD + o0 + r) * DD + i0 + c * 8, &Bs[slot][q * 512]);
    }
  };
  f32x4 acc[4][4];
#pragma unroll
  for (int i = 0; i < 4; ++i)
#pragma unroll
    for (int j = 0; j < 4; ++j) acc[i][j] = f32x4{0.f, 0.f, 0.f, 0.f};
  stageA(0, ibase);
  stageB(0, 0, ibase);
  stageB(1, 1, ibase);
  asm volatile("s_waitcnt vmcnt(0)" ::: "memory");
  __builtin_amdgcn_s_barrier();
  asm volatile("" ::: "memory");
  const int T = 8 * KK;  // 248 rounds
  const int kx = ksid * 64;  // byte XOR selecting this wave's K=32 half (swizzle-compatible)
  for (int t = 0; t < T; ++t) {
    const int i0i = t / KK, k = t - i0i * KK;
    const int tn = t + 2;
    if (tn < T) stageB(tn & 3, tn % KK, ibase + (tn / KK) * 64);
    // A-frag reads first (Ad buffer is barrier-protected at slice granularity)
    const u16* Ab = Ad[i0i & 1];
    s16x8 af[4];
    const int rk0 = wm * 64 + q15 + k;
#pragma unroll
    for (int mf = 0; mf < 4; ++mf) {
      const int rr = rk0 + mf * 16;
      const char* p = (const char*)Ab + rr * 128;
      af[mf] = *(const s16x8*)(p + (((g ^ (rr & 7)) * 16) ^ kx));
    }
    // own B loads landed when <= 2*(rounds still in flight) outstanding
    if (tn < T)          asm volatile("s_waitcnt vmcnt(4)" ::: "memory");
    else if (t + 1 < T)  asm volatile("s_waitcnt vmcnt(2)" ::: "memory");
    else                 asm volatile("s_waitcnt vmcnt(0)" ::: "memory");
    __builtin_amdgcn_s_barrier();                 // all waves' B(t) visible
    asm volatile("" ::: "memory");
    // A prefetch AFTER the wait+barrier so vmcnt(4) never forces a fresh load
    if (k == 5 && i0i < 7) stageA((i0i + 1) & 1, ibase + (i0i + 1) * 64);
    const u16* Bb = Bs[t & 3];
    s16x8 bfr[4];
#pragma unroll
    for (int nf = 0; nf < 4; ++nf) {
      const int rr = wn * 64 + nf * 16 + q15;
      const char* p = (const char*)Bb + rr * 128;
      bfr[nf] = *(const s16x8*)(p + (((g ^ (rr & 7)) * 16) ^ kx));
    }
    __builtin_amdgcn_s_setprio(1);
#pragma unroll
    for (int mf = 0; mf < 4; ++mf)
#pragma unroll
      for (int nf = 0; nf < 4; ++nf)
        acc[mf][nf] = MFMA16(af[mf], bfr[nf], acc[mf][nf]);
    __builtin_amdgcn_s_setprio(0);
  }
  // ---- ks-pair reduction: ks1 waves stash f32 acc in LDS (reuse Bs), ks0 sums+writes ----
  __syncthreads();
  float* scr = (float*)(&Bs[0][0]) + (wm * 2 + wn) * 4096;
  if (ksid == 1) {
#pragma unroll
    for (int mf = 0; mf < 4; ++mf)
#pragma unroll
      for (int nf = 0; nf < 4; ++nf) {
        const int col = nf * 16 + q15;
        *(f32x4*)&scr[col * 64 + ((mf * 16 + g * 4) ^ ((col & 7) << 3))] = acc[mf][nf];
      }
  }
  __syncthreads();
  if (ksid == 0) {
    u16* Pz = P + (size_t)z * NTOK * DD;
#pragma unroll
    for (int mf = 0; mf < 4; ++mf) {
      f32x4 sum[4];
#pragma unroll
      for (int nf = 0; nf < 4; ++nf) {
        const int col = nf * 16 + q15;
        const f32x4 o = *(const f32x4*)&scr[col * 64 + ((mf * 16 + g * 4) ^ ((col & 7) << 3))];
        sum[nf] = acc[mf][nf] + o;
      }
#pragma unroll
      for (int r = 0; r < 4; ++r) {
        const int srow = s0l + wm * 64 + mf * 16 + g * 4 + r;
        u16* orow = Pz + (size_t)(b * SS + srow) * DD + o0 + wn * 64;
#pragma unroll
        for (int nf = 0; nf < 4; ++nf)
          orow[nf * 16 + q15] = f2bf(sum[nf][r]);
      }
    }
  }
}

// ---------------- combine: x1 = gelu(P0+P1+cb) + x ----------------
__global__ void combine_kernel(const u16* __restrict__ P, const float* __restrict__ cb,
                               const float* __restrict__ x, float* __restrict__ x1) {
  const int idx = blockIdx.x * 256 + threadIdx.x;
  const size_t base = (size_t)idx * 4;
  const int col = (int)(base & (DD - 1));
  const u16x4 p0 = *(const u16x4*)(P + base);
  const u16x4 p1 = *(const u16x4*)(P + (size_t)NTOK * DD + base);
  const float4 xv = *(const float4*)(x + base);
  const float4 cbv = *(const float4*)(cb + col);
  float4 o;
  o.x = gelu_f(bf2f(p0[0]) + bf2f(p1[0]) + cbv.x) + xv.x;
  o.y = gelu_f(bf2f(p0[1]) + bf2f(p1[1]) + cbv.y) + xv.y;
  o.z = gelu_f(bf2f(p0[2]) + bf2f(p1[2]) + cbv.z) + xv.z;
  o.w = gelu_f(bf2f(p0[3]) + bf2f(p1[3]) + cbv.w) + xv.w;
  *(float4*)(x1 + base) = o;
}

// ---------------- qkv GEMM: qkvb[2048][3072] = hb @ inwb^T + in_b (bf16 out) ----------------
__global__ __launch_bounds__(256) void qkv_kernel(const u16* __restrict__ A, const u16* __restrict__ B,
                           const float* __restrict__ bias, u16* __restrict__ C) {
  const int n0 = blockIdx.x * 64, m0 = blockIdx.y * 128;
  const int tid = threadIdx.x, lane = tid & 63, w = tid >> 6;
  const int wm = w >> 1, wn = w & 1;
  __shared__ u16 As[2][128 * 64];
  __shared__ u16 Bs[2][64 * 64];
  f32x4 acc[4][2];
#pragma unroll
  for (int i = 0; i < 4; ++i)
#pragma unroll
    for (int j = 0; j < 2; ++j) acc[i][j] = f32x4{0.f, 0.f, 0.f, 0.f};
  auto stage = [&](int t, int buf) {
    const int k0 = t * 64;
#pragma unroll
    for (int q = 0; q < 4; ++q) {
      const int idx = w * 4 + q, r = idx * 8 + (lane >> 3), c = (lane & 7) ^ (r & 7);
      GLOAD16(A + (size_t)(m0 + r) * DD + k0 + c * 8, &As[buf][idx * 512]);
    }
#pragma unroll
    for (int q = 0; q < 2; ++q) {
      const int idx = w * 2 + q, r = idx * 8 + (lane >> 3), c = (lane & 7) ^ (r & 7);
      GLOAD16(B + (size_t)(n0 + r) * DD + k0 + c * 8, &Bs[buf][idx * 512]);
    }
  };
  stage(0, 0);
  asm volatile("s_waitcnt vmcnt(0)" ::: "memory");
  __syncthreads();
  const int T = DD / 64;
  for (int t = 0; t < T; ++t) {
    if (t + 1 < T) stage(t + 1, (t + 1) & 1);
    const u16* Ab = As[t & 1];
    const u16* Bb = Bs[t & 1];
    const int xb = (((lane >> 4) ^ (lane & 7)) * 16);
    s16x8 af[4][2], bfr[2][2];
#pragma unroll
    for (int mf = 0; mf < 4; ++mf) {
      const char* p = (const char*)Ab + (wm * 64 + mf * 16 + (lane & 15)) * 128;
      af[mf][0] = *(const s16x8*)(p + xb);
      af[mf][1] = *(const s16x8*)(p + (xb ^ 64));
    }
#pragma unroll
    for (int nf = 0; nf < 2; ++nf) {
      const char* p = (const char*)Bb + (wn * 32 + nf * 16 + (lane & 15)) * 128;
      bfr[nf][0] = *(const s16x8*)(p + xb);
      bfr[nf][1] = *(const s16x8*)(p + (xb ^ 64));
    }
#pragma unroll
    for (int ks = 0; ks < 2; ++ks)
#pragma unroll
      for (int mf = 0; mf < 4; ++mf)
#pragma unroll
        for (int nf = 0; nf < 2; ++nf)
          acc[mf][nf] = MFMA16(af[mf][ks], bfr[nf][ks], acc[mf][nf]);
    asm volatile("s_waitcnt vmcnt(0)" ::: "memory");
    __syncthreads();
  }
#pragma unroll
  for (int mf = 0; mf < 4; ++mf)
#pragma unroll
    for (int rr = 0; rr < 4; ++rr) {
      const int row = m0 + wm * 64 + mf * 16 + (lane >> 4) * 4 + rr;
#pragma unroll
      for (int nf = 0; nf < 2; ++nf) {
        const int col = n0 + wn * 32 + nf * 16 + (lane & 15);
        C[(size_t)row * D3 + col] = f2bf(acc[mf][nf][rr] + bias[col]);
      }
    }
}

// ---------------- out proj: x2 = ctxb @ outwb^T + out_b + x1 (f32 + bf16 out) ----------------
__global__ __launch_bounds__(256) void out_kernel(const u16* __restrict__ A, const u16* __restrict__ B,
                           const float* __restrict__ bias, const float* __restrict__ resid,
                           float* __restrict__ C, u16* __restrict__ Cb) {
  const int n0 = blockIdx.x * 64, m0 = blockIdx.y * 128;
  const int tid = threadIdx.x, lane = tid & 63, w = tid >> 6;
  const int wm = w >> 1, wn = w & 1;
  __shared__ u16 As[2][128 * 64];
  __shared__ u16 Bs[2][64 * 64];
  f32x4 acc[4][2];
#pragma unroll
  for (int i = 0; i < 4; ++i)
#pragma unroll
    for (int j = 0; j < 2; ++j) acc[i][j] = f32x4{0.f, 0.f, 0.f, 0.f};
  auto stage = [&](int t, int buf) {
    const int k0 = t * 64;
#pragma unroll
    for (int q = 0; q < 4; ++q) {
      const int idx = w * 4 + q, r = idx * 8 + (lane >> 3), c = (lane & 7) ^ (r & 7);
      GLOAD16(A + (size_t)(m0 + r) * DD + k0 + c * 8, &As[buf][idx * 512]);
    }
#pragma unroll
    for (int q = 0; q < 2; ++q) {
      const int idx = w * 2 + q, r = idx * 8 + (lane >> 3), c = (lane & 7) ^ (r & 7);
      GLOAD16(B + (size_t)(n0 + r) * DD + k0 + c * 8, &Bs[buf][idx * 512]);
    }
  };
  stage(0, 0);
  asm volatile("s_waitcnt vmcnt(0)" ::: "memory");
  __syncthreads();
  const int T = DD / 64;
  for (int t = 0; t < T; ++t) {
    if (t + 1 < T) stage(t + 1, (t + 1) & 1);
    const u16* Ab = As[t & 1];
    const u16* Bb = Bs[t & 1];
    const int xb = (((lane >> 4) ^ (lane & 7)) * 16);
    s16x8 af[4][2], bfr[2][2];
#pragma unroll
    for (int mf = 0; mf < 4; ++mf) {
      const char* p = (const char*)Ab + (wm * 64 + mf * 16 + (lane & 15)) * 128;
      af[mf][0] = *(const s16x8*)(p + xb);
      af[mf][1] = *(const s16x8*)(p + (xb ^ 64));
    }
#pragma unroll
    for (int nf = 0; nf < 2; ++nf) {
      const char* p = (const char*)Bb + (wn * 32 + nf * 16 + (lane & 15)) * 128;
      bfr[nf][0] = *(const s16x8*)(p + xb);
      bfr[nf][1] = *(const s16x8*)(p + (xb ^ 64));
    }
#pragma unroll
    for (int ks = 0; ks < 2; ++ks)
#pragma unroll
      for (int mf = 0; mf < 4; ++mf)
#pragma unroll
        for (int nf = 0; nf < 2; ++nf)
          acc[mf][nf] = MFMA16(af[mf][ks], bfr[nf][ks], acc[mf][nf]);
    asm volatile("s_waitcnt vmcnt(0)" ::: "memory");
    __syncthreads();
  }
#pragma unroll
  for (int mf = 0; mf < 4; ++mf)
#pragma unroll
    for (int rr = 0; rr < 4; ++rr) {
      const int row = m0 + wm * 64 + mf * 16 + (lane >> 4) * 4 + rr;
#pragma unroll
      for (int nf = 0; nf < 2; ++nf) {
        const int col = n0 + wn * 32 + nf * 16 + (lane & 15);
        const float v = acc[mf][nf][rr] + bias[col] + resid[(size_t)row * DD + col];
        C[(size_t)row * DD + col] = v;
        Cb[(size_t)row * DD + col] = f2bf(v);
      }
    }
}

// ---------------- MFMA flash attention: 128 q x (b,h) per block, 8 waves x 16 q ----------------
__global__ __launch_bounds__(512) void attn_kernel(const u16* __restrict__ qkv,
                                                   const u16* __restrict__ Vt,
                                                   u16* __restrict__ ctx) {
  const int q0 = blockIdx.x * 128, h = blockIdx.y, b = blockIdx.z;
  const int tid = threadIdx.x, lane = tid & 63, w = tid >> 6;
  const int q15 = lane & 15, g = lane >> 4, l7 = lane & 7;
  __shared__ u16 Q_lds[128 * 64];
  __shared__ u16 K_lds[2][64 * 64];
  __shared__ u16 V_lds[2][64 * 64];
  __shared__ u16 P_lds[8][16 * 72];
  __shared__ float s_lds[8][16];

#pragma unroll
  for (int q2 = 0; q2 < 2; ++q2) {
    const int idx = w * 2 + q2;
    const int r = idx * 8 + (lane >> 3);
    const int c = l7 ^ (r & 7);
    GLOAD16(qkv + (size_t)(b * SS + q0 + r) * D3 + h * HDIM + c * 8, &Q_lds[idx * 512]);
  }
  auto stageK = [&](int buf, int kt) {
    const int r = w * 8 + (lane >> 3);
    const int c = l7 ^ (r & 7);
    GLOAD16(qkv + (size_t)(b * SS + kt * 64 + r) * D3 + DD + h * HDIM + c * 8,
            &K_lds[buf][w * 512]);
  };
  auto stageV = [&](int buf, int kt) {
    const int r = w * 8 + (lane >> 3);
    const int c = l7 ^ (r & 7);
    GLOAD16(Vt + ((size_t)(b * HH + h) * HDIM + r) * SS + kt * 64 + c * 8,
            &V_lds[buf][w * 512]);
  };
  stageK(0, 0);
  stageV(0, 0);
  asm volatile("s_waitcnt vmcnt(0)" ::: "memory");
  __syncthreads();
  s16x8 bq[2];
#pragma unroll
  for (int ks = 0; ks < 2; ++ks)
    bq[ks] = *(const s16x8*)((const char*)Q_lds + (w * 16 + q15) * 128 + ((4 * ks + g) ^ l7) * 16);
  f32x4 oacc[4];
#pragma unroll
  for (int nf = 0; nf < 4; ++nf) oacc[nf] = f32x4{0.f, 0.f, 0.f, 0.f};
  float mrun = -3.0e38f, lrun = 0.0f;
  int buf = 0;
  for (int kt = 0; kt < 16; ++kt) {
    if (kt < 15) { stageK(buf ^ 1, kt + 1); stageV(buf ^ 1, kt + 1); }
    f32x4 st[4];
#pragma unroll
    for (int mf = 0; mf < 4; ++mf) st[mf] = f32x4{0.f, 0.f, 0.f, 0.f};
#pragma unroll
    for (int ks = 0; ks < 2; ++ks) {
#pragma unroll
      for (int mf = 0; mf < 4; ++mf) {
        const s16x8 ka = *(const s16x8*)((const char*)K_lds[buf] + (mf * 16 + q15) * 128 +
                                         ((4 * ks + g) ^ l7) * 16);
        st[mf] = MFMA16(ka, bq[ks], st[mf]);
      }
    }
    float t0[4][4];
    float cmax = -3.0e38f;
#pragma unroll
    for (int mf = 0; mf < 4; ++mf)
#pragma unroll
      for (int r = 0; r < 4; ++r) {
        const float v = st[mf][r] * 0.125f;
        t0[mf][r] = v;
        cmax = fmaxf(cmax, v);
      }
    cmax = fmaxf(cmax, __shfl_xor(cmax, 16));
    cmax = fmaxf(cmax, __shfl_xor(cmax, 32));
    const float mnew = fmaxf(mrun, cmax);
    const float scf = __expf(mrun - mnew);
    float psum = 0.f;
#pragma unroll
    for (int mf = 0; mf < 4; ++mf)
#pragma unroll
      for (int r = 0; r < 4; ++r) {
        const float p = __expf(t0[mf][r] - mnew);
        t0[mf][r] = p;
        psum += p;
      }
    psum += __shfl_xor(psum, 16);
    psum += __shfl_xor(psum, 32);
    lrun = lrun * scf + psum;
    mrun = mnew;
    s_lds[w][q15] = scf;
    u16* pw = &P_lds[w][0];
#pragma unroll
    for (int mf = 0; mf < 4; ++mf) {
      u32x2 pk;
      pk[0] = (unsigned)f2bf(t0[mf][0]) | ((unsigned)f2bf(t0[mf][1]) << 16);
      pk[1] = (unsigned)f2bf(t0[mf][2]) | ((unsigned)f2bf(t0[mf][3]) << 16);
      *(u32x2*)(pw + q15 * 72 + mf * 16 + g * 4) = pk;
    }
    asm volatile("s_waitcnt lgkmcnt(0)" ::: "memory");
    const f32x4 scv = *(const f32x4*)&s_lds[w][g * 4];
#pragma unroll
    for (int nf = 0; nf < 4; ++nf)
#pragma unroll
      for (int r = 0; r < 4; ++r) oacc[nf][r] *= scv[r];
#pragma unroll
    for (int ks = 0; ks < 2; ++ks) {
      const s16x8 pa = *(const s16x8*)(pw + q15 * 72 + ks * 32 + g * 8);
#pragma unroll
      for (int nf = 0; nf < 4; ++nf) {
        const s16x8 bv = *(const s16x8*)((const char*)V_lds[buf] + (nf * 16 + q15) * 128 +
                                         ((4 * ks + g) ^ l7) * 16);
        oacc[nf] = MFMA16(pa, bv, oacc[nf]);
      }
    }
    asm volatile("s_waitcnt vmcnt(0)" ::: "memory");
    __syncthreads();
    buf ^= 1;
  }
  const float linv = 1.0f / lrun;
  s_lds[w][q15] = linv;
  asm volatile("s_waitcnt lgkmcnt(0)" ::: "memory");
  const f32x4 lv = *(const f32x4*)&s_lds[w][g * 4];
#pragma unroll
  for (int nf = 0; nf < 4; ++nf)
#pragma unroll
    for (int r = 0; r < 4; ++r) {
      const int qg = q0 + w * 16 + g * 4 + r;
      ctx[(size_t)(b * SS + qg) * DD + h * HDIM + nf * 16 + q15] = f2bf(oacc[nf][r] * lv[r]);
    }
}

// ---------------- MoE routing ----------------
__global__ void zero_counts_kernel(int* c) { if (threadIdx.x < GG) c[threadIdx.x] = 0; }

__global__ void gather_kernel(const int* __restrict__ gid, int* __restrict__ counts,
                              int* __restrict__ gather) {
  const int n = blockIdx.x * 256 + threadIdx.x;
  if (n < NTOK) {
    const int g = gid[n];
    const int slot = atomicAdd(&counts[g], 1);
    gather[g * NTOK + slot] = n;
  }
}

// off[g] = exclusive prefix sum of counts; off[GG] = NTOK
__global__ void scan_kernel(const int* __restrict__ cnts, int* __restrict__ off) {
  if (threadIdx.x == 0) {
    int s = 0;
#pragma unroll
    for (int g = 0; g < GG; ++g) { off[g] = s; s += cnts[g]; }
    off[GG] = s;
  }
}

// gidx[off[g]+slot] = gat[g*NTOK+slot]  (slot-packed token list)
__global__ void pack_kernel(const int* __restrict__ gat, const int* __restrict__ cnts,
                            const int* __restrict__ off, int* __restrict__ gidx) {
  const int g = blockIdx.y;
  const int slot = blockIdx.x * 256 + threadIdx.x;
  if (slot < cnts[g]) gidx[off[g] + slot] = gat[g * NTOK + slot];
}

// x2g[sg][:] = x2b[gidx[sg]][:]   (one row per block, 256 threads x 4 elems)
__global__ void gatx_kernel(const u16* __restrict__ x2b, const int* __restrict__ gidx,
                            u16* __restrict__ x2g) {
  const int sg = blockIdx.x;
  const int tok = gidx[sg];
  *(u16x4*)(x2g + (size_t)sg * DD + threadIdx.x * 4) =
      *(const u16x4*)(x2b + (size_t)tok * DD + threadIdx.x * 4);
}

// ---------------- MoE GEMM1: h1[e][base+slot] = gelu(x2g[base+slot] @ w1t[g,e]^T + b1) ----------------
// A fully contiguous (slot-packed); no gather anywhere in the K-loop.
__global__ __launch_bounds__(256) void moe1_kernel(const u16* __restrict__ x2g, const u16* __restrict__ w1t,
                            const float* __restrict__ e_b1, const int* __restrict__ off,
                            const int* __restrict__ cnts, u16* __restrict__ h1) {
  const int ge = blockIdx.z, g = ge >> 1, e = ge & 1;
  const int cnt = cnts[g];
  const int m0 = blockIdx.x * 128;
  if (m0 >= cnt) return;
  const int base = off[g];
  const int n0 = blockIdx.y * 64;
  const u16* A = x2g + (size_t)base * DD;       // contiguous rows of this group
  const u16* B = w1t + (size_t)ge * HIDN * DD;  // [HID][D]
  const int tid = threadIdx.x, lane = tid & 63, w = tid >> 6;
  const int wm = w >> 1, wn = w & 1;
  __shared__ u16 As[2][128 * 64];
  __shared__ u16 Bs[2][64 * 64];
  f32x4 acc[4][2];
#pragma unroll
  for (int i = 0; i < 4; ++i)
#pragma unroll
    for (int j = 0; j < 2; ++j) acc[i][j] = f32x4{0.f, 0.f, 0.f, 0.f};
  auto stage = [&](int t, int buf) {
    const int k0 = t * 64;
#pragma unroll
    for (int q = 0; q < 4; ++q) {
      const int idx = w * 4 + q, r = idx * 8 + (lane >> 3), c = (lane & 7) ^ (r & 7);
      int rg = m0 + r; if (rg > cnt - 1) rg = cnt - 1;
      GLOAD16(A + (size_t)rg * DD + k0 + c * 8, &As[buf][idx * 512]);
    }
#pragma unroll
    for (int q = 0; q < 2; ++q) {
      const int idx = w * 2 + q, r = idx * 8 + (lane >> 3), c = (lane & 7) ^ (r & 7);
      GLOAD16(B + (size_t)(n0 + r) * DD + k0 + c * 8, &Bs[buf][idx * 512]);
    }
  };
  stage(0, 0);
  asm volatile("s_waitcnt vmcnt(0)" ::: "memory");
  __syncthreads();
  const int T = DD / 64;
  for (int t = 0; t < T; ++t) {
    if (t + 1 < T) stage(t + 1, (t + 1) & 1);
    const u16* Ab = As[t & 1];
    const u16* Bb = Bs[t & 1];
    const int xb = (((lane >> 4) ^ (lane & 7)) * 16);
    s16x8 af[4][2], bfr[2][2];
#pragma unroll
    for (int mf = 0; mf < 4; ++mf) {
      const char* p = (const char*)Ab + (wm * 64 + mf * 16 + (lane & 15)) * 128;
      af[mf][0] = *(const s16x8*)(p + xb);
      af[mf][1] = *(const s16x8*)(p + (xb ^ 64));
    }
#pragma unroll
    for (int nf = 0; nf < 2; ++nf) {
      const char* p = (const char*)Bb + (wn * 32 + nf * 16 + (lane & 15)) * 128;
      bfr[nf][0] = *(const s16x8*)(p + xb);
      bfr[nf][1] = *(const s16x8*)(p + (xb ^ 64));
    }
#pragma unroll
    for (int ks = 0; ks < 2; ++ks)
#pragma unroll
      for (int mf = 0; mf < 4; ++mf)
#pragma unroll
        for (int nf = 0; nf < 2; ++nf)
          acc[mf][nf] = MFMA16(af[mf][ks], bfr[nf][ks], acc[mf][nf]);
    asm volatile("s_waitcnt vmcnt(0)" ::: "memory");
    __syncthreads();
  }
  const float* b1 = e_b1 + (size_t)ge * HIDN;
#pragma unroll
  for (int mf = 0; mf < 4; ++mf)
#pragma unroll
    for (int rr = 0; rr < 4; ++rr) {
      const int rowg = m0 + wm * 64 + mf * 16 + (lane >> 4) * 4 + rr;
      if (rowg < cnt) {
        u16* orow = h1 + ((size_t)e * NTOK + base + rowg) * HIDN;  // slot-ordered
#pragma unroll
        for (int nf = 0; nf < 2; ++nf) {
          const int col = n0 + wn * 32 + nf * 16 + (lane & 15);
          orow[col] = f2bf(gelu_f(acc[mf][nf][rr] + b1[col]));
        }
      }
    }
}

// ---------------- MoE GEMM2: out[tok] = 0.5*sum_e h1[e][slot] @ w2t[g,e]^T + 0.5*(b2_0+b2_1) + x2 ----------------
// A contiguous (slot-ordered h1); scatter only in the epilogue.
__global__ __launch_bounds__(256) void moe2_kernel(const u16* __restrict__ h1, const u16* __restrict__ w2t,
                            const float* __restrict__ e_b2, const int* __restrict__ off,
                            const int* __restrict__ cnts, const int* __restrict__ gidx,
                            const float* __restrict__ x2, float* __restrict__ outp) {
  const int g = blockIdx.z;
  const int cnt = cnts[g];
  const int m0 = blockIdx.x * 128;
  if (m0 >= cnt) return;
  const int base = off[g];
  const int n0 = blockIdx.y * 64;
  const int tid = threadIdx.x, lane = tid & 63, w = tid >> 6;
  const int wm = w >> 1, wn = w & 1;
  __shared__ u16 As[2][128 * 64];
  __shared__ u16 Bs[2][64 * 64];
  f32x4 acc[4][2];
#pragma unroll
  for (int i = 0; i < 4; ++i)
#pragma unroll
    for (int j = 0; j < 2; ++j) acc[i][j] = f32x4{0.f, 0.f, 0.f, 0.f};
  auto stage = [&](int t, int buf) {
    const int e = t >> 5;
    const int k0 = (t & 31) * 64;
#pragma unroll
    for (int q = 0; q < 4; ++q) {
      const int idx = w * 4 + q, r = idx * 8 + (lane >> 3), c = (lane & 7) ^ (r & 7);
      int rg = m0 + r; if (rg > cnt - 1) rg = cnt - 1;
      GLOAD16(h1 + ((size_t)e * NTOK + base + rg) * HIDN + k0 + c * 8, &As[buf][idx * 512]);
    }
#pragma unroll
    for (int q = 0; q < 2; ++q) {
      const int idx = w * 2 + q, r = idx * 8 + (lane >> 3), c = (lane & 7) ^ (r & 7);
      GLOAD16(w2t + ((size_t)(g * EE + e) * DD + n0 + r) * HIDN + k0 + c * 8, &Bs[buf][idx * 512]);
    }
  };
  stage(0, 0);
  asm volatile("s_waitcnt vmcnt(0)" ::: "memory");
  __syncthreads();
  const int T = 64;
  for (int t = 0; t < T; ++t) {
    if (t + 1 < T) stage(t + 1, (t + 1) & 1);
    const u16* Ab = As[t & 1];
    const u16* Bb = Bs[t & 1];
    const int xb = (((lane >> 4) ^ (lane & 7)) * 16);
    s16x8 af[4][2], bfr[2][2];
#pragma unroll
    for (int mf = 0; mf < 4; ++mf) {
      const char* p = (const char*)Ab + (wm * 64 + mf * 16 + (lane & 15)) * 128;
      af[mf][0] = *(const s16x8*)(p + xb);
      af[mf][1] = *(const s16x8*)(p + (xb ^ 64));
    }
#pragma unroll
    for (int nf = 0; nf < 2; ++nf) {
      const char* p = (const char*)Bb + (wn * 32 + nf * 16 + (lane & 15)) * 128;
      bfr[nf][0] = *(const s16x8*)(p + xb);
      bfr[nf][1] = *(const s16x8*)(p + (xb ^ 64));
    }
#pragma unroll
    for (int ks = 0; ks < 2; ++ks)
#pragma unroll
      for (int mf = 0; mf < 4; ++mf)
#pragma unroll
        for (int nf = 0; nf < 2; ++nf)
          acc[mf][nf] = MFMA16(af[mf][ks], bfr[nf][ks], acc[mf][nf]);
    asm volatile("s_waitcnt vmcnt(0)" ::: "memory");
    __syncthreads();
  }
  const float* b20 = e_b2 + (size_t)(g * EE + 0) * DD;
  const float* b21 = e_b2 + (size_t)(g * EE + 1) * DD;
#pragma unroll
  for (int mf = 0; mf < 4; ++mf)
#pragma unroll
    for (int rr = 0; rr < 4; ++rr) {
      const int rowg = m0 + wm * 64 + mf * 16 + (lane >> 4) * 4 + rr;
      if (rowg < cnt) {
        const int tok = gidx[base + rowg];
#pragma unroll
        for (int nf = 0; nf < 2; ++nf) {
          const int col = n0 + wn * 32 + nf * 16 + (lane & 15);
          outp[(size_t)tok * DD + col] =
              0.5f * acc[mf][nf][rr] + 0.5f * (b20[col] + b21[col]) + x2[(size_t)tok * DD + col];
        }
      }
    }
}

extern "C" void kernel_launch(void* const* d_in, const int* in_sizes, int n_in,
                              void* d_out, int out_size, void* d_ws, size_t ws_size,
                              hipStream_t stream) {
  (void)in_sizes; (void)n_in; (void)out_size; (void)ws_size;
  const float* x      = (const float*)d_in[0];
  const int*   gid    = (const int*)d_in[1];
  const float* cn_g   = (const float*)d_in[2];
  const float* cn_b   = (const float*)d_in[3];
  const float* conv_w = (const float*)d_in[4];
  const float* conv_b = (const float*)d_in[5];
  const float* an_g   = (const float*)d_in[6];
  const float* an_b   = (const float*)d_in[7];
  const float* in_w   = (const float*)d_in[8];
  const float* in_b   = (const float*)d_in[9];
  const float* out_w  = (const float*)d_in[10];
  const float* out_b  = (const float*)d_in[11];
  const float* e_w1   = (const float*)d_in[12];
  const float* e_b1   = (const float*)d_in[13];
  const float* e_w2   = (const float*)d_in[14];
  const float* e_b2   = (const float*)d_in[15];
  float* outp = (float*)d_out;

  // ---- workspace map (high-water 74MB + ~41KB) ----
  char* wsp = (char*)d_ws;
  u16*   hb    = (u16*)(wsp);                         // 0..4M  (ln out; ctxb reuse)
  u16*   Pc    = (u16*)(wsp + (4ull << 20));          // 4..12M (conv partials x2, conv phase)
  float* x1    = (float*)(wsp + (12ull << 20));       // 12..20M (combine out; dead after out_kernel)
  u16*   Wb    = (u16*)(wsp + (12ull << 20));         // 12..74M (conv phase only; x1 written after)
  u16*   qkvb  = (u16*)(wsp + (24ull << 20));         // 24..36M (qkv->attn)
  u16*   inwb  = (u16*)(wsp + (40ull << 20));         // 40..46M (qkv phase)
  u16*   outwb = (u16*)(wsp + (40ull << 20));         // 40..42M (out phase, after qkv)
  u16*   Vt    = (u16*)(wsp + (46ull << 20));         // 46..50M (attn phase)
  u16*   ctxb  = hb;                                  // 0..4M  (after qkv)
  float* x2    = (float*)(wsp + (52ull << 20));       // 52..60M
  u16*   x2b   = (u16*)(wsp + (60ull << 20));         // 60..64M
  u16*   x2g   = (u16*)(wsp + (64ull << 20));         // 64..68M (slot-packed tokens, MoE phase)
  u16*   wgt   = (u16*)(wsp + (4ull << 20));          // 4..36M (w1t, then w2t; MoE phase)
  u16*   h1    = (u16*)(wsp + (36ull << 20));         // 36..52M (MoE phase, slot-ordered)
  int*   gat   = (int*)(wsp + (74ull << 20));         // 32KB
  int*   cnts  = gat + GG * NTOK;                     // 16B
  int*   offp  = cnts + GG;                           // 20B
  int*   gidx  = offp + (GG + 1);                     // 8KB

  // ---- conv block (v2, measured 208us) ----
  ln_kernel<<<NTOK, 256, 0, stream>>>(x, cn_g, cn_b, hb);
  prep_convw<<<1024, 256, 0, stream>>>(conv_w, Wb);
  conv_kernel<<<256, 512, 0, stream>>>(hb, Wb, Pc);
  combine_kernel<<<NTOK * DD / 1024, 256, 0, stream>>>(Pc, conv_b, x, x1);
  // ---- attention block ----
  ln_kernel<<<NTOK, 256, 0, stream>>>(x1, an_g, an_b, hb);
  cvt_kernel<<<3072, 256, 0, stream>>>(in_w, inwb, 3 * DD * DD / 4);
  qkv_kernel<<<dim3(D3 / 64, NTOK / 128), 256, 0, stream>>>(hb, inwb, in_b, qkvb);
  vtr_kernel<<<dim3(SS / 32, HDIM / 32, BB * HH), 256, 0, stream>>>(qkvb, Vt);
  attn_kernel<<<dim3(SS / 128, HH, BB), 512, 0, stream>>>(qkvb, Vt, ctxb);
  cvt_kernel<<<1024, 256, 0, stream>>>(out_w, outwb, DD * DD / 4);
  out_kernel<<<dim3(DD / 64, NTOK / 128), 256, 0, stream>>>(ctxb, outwb, out_b, x1, x2, x2b);
  // ---- MoE (slot-packed: contiguous GEMMs, scatter only at the end) ----
  zero_counts_kernel<<<1, 64, 0, stream>>>(cnts);
  gather_kernel<<<NTOK / 256, 256, 0, stream>>>(gid, cnts, gat);
  scan_kernel<<<1, 64, 0, stream>>>(cnts, offp);
  pack_kernel<<<dim3(NTOK / 256, GG), 256, 0, stream>>>(gat, cnts, offp, gidx);
  gatx_kernel<<<NTOK, 256, 0, stream>>>(x2b, gidx, x2g);
  tr_kernel<<<dim3(HIDN / 32, DD / 32, GG * EE), 256, 0, stream>>>(e_w1, wgt, DD, HIDN);
  moe1_kernel<<<dim3(NTOK / 128, HIDN / 64, GG * EE), 256, 0, stream>>>(x2g, wgt, e_b1, offp, cnts, h1);
  tr_kernel<<<dim3(DD / 32, HIDN / 32, GG * EE), 256, 0, stream>>>(e_w2, wgt, HIDN, DD);
  moe2_kernel<<<dim3(NTOK / 128, DD / 64, GG), 256, 0, stream>>>(h1, wgt, e_b2, offp, cnts, gidx, x2, outp);
}

// Round 5
// 526.558 us; speedup vs baseline: 1.3570x; 1.2992x over previous
//
#include <hip/hip_runtime.h>
#include <hip/hip_bf16.h>
#include <math.h>

#define BB 2
#define SS 1024
#define DD 1024
#define HH 16
#define HDIM 64
#define KK 31
#define GG 4
#define EE 2
#define HIDN 2048
#define NTOK (BB*SS)
#define D3 (3*DD)

typedef unsigned short u16;
typedef __attribute__((ext_vector_type(8))) short s16x8;
typedef __attribute__((ext_vector_type(8))) unsigned short u16x8;
typedef __attribute__((ext_vector_type(4))) unsigned short u16x4;
typedef __attribute__((ext_vector_type(4))) float f32x4;
typedef __attribute__((ext_vector_type(2))) unsigned int u32x2;

__device__ __forceinline__ float gelu_f(float x) {
  return 0.5f * x * (1.0f + erff(x * 0.7071067811865475f));
}
__device__ __forceinline__ u16 f2bf(float f) {
  unsigned u = __builtin_bit_cast(unsigned, f);
  u = (u + 0x7fffu + ((u >> 16) & 1u)) >> 16;
  return (u16)u;
}
__device__ __forceinline__ float bf2f(u16 u) {
  return __builtin_bit_cast(float, ((unsigned)u) << 16);
}
__device__ __forceinline__ f32x4 MFMA16(s16x8 a, s16x8 b, f32x4 c) {
  return __builtin_amdgcn_mfma_f32_16x16x32_bf16(a, b, c, 0, 0, 0);
}
#define GLOAD16(gp, lp) __builtin_amdgcn_global_load_lds( \
    (const __attribute__((address_space(1))) void*)(gp),  \
    (__attribute__((address_space(3))) void*)(lp), 16, 0, 0)

// ---------------- LayerNorm: fp32 in -> bf16 out, one block per row ----------------
__global__ void ln_kernel(const float* __restrict__ x, const float* __restrict__ g,
                          const float* __restrict__ b, u16* __restrict__ out) {
  const int row = blockIdx.x;
  const int tid = threadIdx.x;
  __shared__ float red[4];
  const float4 v = reinterpret_cast<const float4*>(x + (size_t)row * DD)[tid];
  float s = v.x + v.y + v.z + v.w;
  s += __shfl_down(s, 32); s += __shfl_down(s, 16); s += __shfl_down(s, 8);
  s += __shfl_down(s, 4);  s += __shfl_down(s, 2);  s += __shfl_down(s, 1);
  if ((tid & 63) == 0) red[tid >> 6] = s;
  __syncthreads();
  const float mean = (red[0] + red[1] + red[2] + red[3]) * (1.0f / DD);
  __syncthreads();
  const float4 d = make_float4(v.x - mean, v.y - mean, v.z - mean, v.w - mean);
  float sq = d.x*d.x + d.y*d.y + d.z*d.z + d.w*d.w;
  sq += __shfl_down(sq, 32); sq += __shfl_down(sq, 16); sq += __shfl_down(sq, 8);
  sq += __shfl_down(sq, 4);  sq += __shfl_down(sq, 2);  sq += __shfl_down(sq, 1);
  if ((tid & 63) == 0) red[tid >> 6] = sq;
  __syncthreads();
  const float var = (red[0] + red[1] + red[2] + red[3]) * (1.0f / DD);
  const float rstd = rsqrtf(var + 1e-5f);
  const float4 gv = reinterpret_cast<const float4*>(g)[tid];
  const float4 bv = reinterpret_cast<const float4*>(b)[tid];
  u16x4 o;
  o[0] = f2bf(d.x * rstd * gv.x + bv.x);
  o[1] = f2bf(d.y * rstd * gv.y + bv.y);
  o[2] = f2bf(d.z * rstd * gv.z + bv.z);
  o[3] = f2bf(d.w * rstd * gv.w + bv.w);
  *reinterpret_cast<u16x4*>(out + (size_t)row * DD + tid * 4) = o;
}

// ---------------- conv weight reorder: conv_w[o][i][k] f32 -> Wb[k][o][i] bf16 ----------------
__global__ void prep_convw(const float* __restrict__ cw, u16* __restrict__ Wb) {
  const int o = blockIdx.x;
#pragma unroll
  for (int rep = 0; rep < 4; ++rep) {
    const int i = rep * 256 + threadIdx.x;
    const float* src = cw + ((size_t)o * DD + i) * KK;
    float wv[KK];
#pragma unroll
    for (int k = 0; k < KK; ++k) wv[k] = src[k];
#pragma unroll
    for (int k = 0; k < KK; ++k)
      Wb[((size_t)k * DD + o) * DD + i] = f2bf(wv[k]);
  }
}

// ---------------- plain f32 -> bf16 convert ----------------
__global__ void cvt_kernel(const float* __restrict__ in, u16* __restrict__ outp, int n4) {
  const int i = blockIdx.x * 256 + threadIdx.x;
  if (i < n4) {
    const float4 v = reinterpret_cast<const float4*>(in)[i];
    u16x4 o; o[0] = f2bf(v.x); o[1] = f2bf(v.y); o[2] = f2bf(v.z); o[3] = f2bf(v.w);
    reinterpret_cast<u16x4*>(outp)[i] = o;
  }
}

// ---------------- transpose-convert: src[z][R][C] f32 -> dst[z][C][R] bf16 ----------------
__global__ void tr_kernel(const float* __restrict__ src, u16* __restrict__ dst, int R, int C) {
  __shared__ float tile[32][33];
  const int c0 = blockIdx.x * 32, r0 = blockIdx.y * 32;
  const size_t base = (size_t)blockIdx.z * R * C;
  const int tx = threadIdx.x & 31, ty = threadIdx.x >> 5;  // ty 0..7
#pragma unroll
  for (int i = 0; i < 4; ++i)
    tile[ty + i * 8][tx] = src[base + (size_t)(r0 + ty + i * 8) * C + c0 + tx];
  __syncthreads();
#pragma unroll
  for (int i = 0; i < 4; ++i)
    dst[base + (size_t)(c0 + ty + i * 8) * R + r0 + tx] = f2bf(tile[tx][ty + i * 8]);
}

// ---------------- V transpose: qkvb V-part -> Vt[b][h][d][k] bf16 ----------------
__global__ void vtr_kernel(const u16* __restrict__ qkvb, u16* __restrict__ Vt) {
  __shared__ u16 tile[32][40];
  const int k0 = blockIdx.x * 32, d0 = blockIdx.y * 32, bh = blockIdx.z;
  const int b = bh >> 4, h = bh & 15;
  const int tx = threadIdx.x & 31, ty = threadIdx.x >> 5;  // ty 0..7
#pragma unroll
  for (int i = 0; i < 4; ++i)
    tile[ty + i * 8][tx] =
        qkvb[(size_t)(b * SS + k0 + ty + i * 8) * D3 + 2 * DD + h * HDIM + d0 + tx];
  __syncthreads();
#pragma unroll
  for (int i = 0; i < 4; ++i)
    Vt[((size_t)(b * HH + h) * HDIM + d0 + ty + i * 8) * SS + k0 + tx] = tile[tx][ty + i * 8];
}

// ---------------- conv via MFMA v2 (measured 208us): 8 waves, shared ring-4 B staging ----------------
__global__ __launch_bounds__(512) void conv_kernel(const u16* __restrict__ hb,
                                                   const u16* __restrict__ Wb,
                                                   u16* __restrict__ P) {
  const int L = blockIdx.x;            // 0..255
  const int o_t = L & 7;               // o-tile pinned per XCD (B L2 reuse)
  const int rest = L >> 3;
  const int s_t = rest >> 1;           // 0..15
  const int z = rest & 1;              // i-half
  const int b = s_t >> 3, sloc = s_t & 7;
  const int s0l = sloc * 128;
  const int o0 = o_t * 128;
  const int ibase = z * 512;
  const int tid = threadIdx.x, lane = tid & 63, w = tid >> 6;
  const int wm = (w >> 2) & 1, wn = (w >> 1) & 1, ksid = w & 1;
  const int q15 = lane & 15, g = lane >> 4;
  __shared__ __align__(16) u16 Ad[2][160 * 64];   // 40 KB, dbuf over i-slices
  __shared__ __align__(16) u16 Bs[4][128 * 64];   // 64 KB, shared ring-4
  const int rlo = (sloc == 0) ? 15 : 0;
  const int rhi = (sloc == 7) ? 143 : 158;
  if (sloc == 0)
    for (int i = tid; i < 15 * 64; i += 512) { Ad[0][i] = 0; Ad[1][i] = 0; }
  if (sloc == 7)
    for (int i = tid; i < 17 * 64; i += 512) { Ad[0][143 * 64 + i] = 0; Ad[1][143 * 64 + i] = 0; }
  auto stageA = [&](int buf, int i0) {
    for (int q = w; q < 20; q += 8) {
      const int r = q * 8 + (lane >> 3);
      const int c = (lane & 7) ^ (r & 7);
      if (r >= rlo && r < rhi)
        GLOAD16(hb + (size_t)(b * SS + s0l - 15 + r) * DD + i0 + c * 8, &Ad[buf][q * 512]);
    }
  };
  auto stageB = [&](int slot, int k, int i0) {  // 128o x 64i, 2 gloads/wave
#pragma unroll
    for (int qq = 0; qq < 2; ++qq) {
      const int q = w * 2 + qq;
      const int r = q * 8 + (lane >> 3);        // 0..127 o-row
      const int c = (lane & 7) ^ (r & 7);
      GLOAD16(Wb + ((size_t)k * DD + o0 + r) * DD + i0 + c * 8, &Bs[slot][q * 512]);
    }
  };
  f32x4 acc[4][4];
#pragma unroll
  for (int i = 0; i < 4; ++i)
#pragma unroll
    for (int j = 0; j < 4; ++j) acc[i][j] = f32x4{0.f, 0.f, 0.f, 0.f};
  stageA(0, ibase);
  stageB(0, 0, ibase);
  stageB(1, 1, ibase);
  asm volatile("s_waitcnt vmcnt(0)" ::: "memory");
  __builtin_amdgcn_s_barrier();
  asm volatile("" ::: "memory");
  const int T = 8 * KK;  // 248 rounds
  const int kx = ksid * 64;  // byte XOR selecting this wave's K=32 half (swizzle-compatible)
  for (int t = 0; t < T; ++t) {
    const int i0i = t / KK, k = t - i0i * KK;
    const int tn = t + 2;
    if (tn < T) stageB(tn & 3, tn % KK, ibase + (tn / KK) * 64);
    // A-frag reads first (Ad buffer is barrier-protected at slice granularity)
    const u16* Ab = Ad[i0i & 1];
    s16x8 af[4];
    const int rk0 = wm * 64 + q15 + k;
#pragma unroll
    for (int mf = 0; mf < 4; ++mf) {
      const int rr = rk0 + mf * 16;
      const char* p = (const char*)Ab + rr * 128;
      af[mf] = *(const s16x8*)(p + (((g ^ (rr & 7)) * 16) ^ kx));
    }
    // own B loads landed when <= 2*(rounds still in flight) outstanding
    if (tn < T)          asm volatile("s_waitcnt vmcnt(4)" ::: "memory");
    else if (t + 1 < T)  asm volatile("s_waitcnt vmcnt(2)" ::: "memory");
    else                 asm volatile("s_waitcnt vmcnt(0)" ::: "memory");
    __builtin_amdgcn_s_barrier();                 // all waves' B(t) visible
    asm volatile("" ::: "memory");
    // A prefetch AFTER the wait+barrier so vmcnt(4) never forces a fresh load
    if (k == 5 && i0i < 7) stageA((i0i + 1) & 1, ibase + (i0i + 1) * 64);
    const u16* Bb = Bs[t & 3];
    s16x8 bfr[4];
#pragma unroll
    for (int nf = 0; nf < 4; ++nf) {
      const int rr = wn * 64 + nf * 16 + q15;
      const char* p = (const char*)Bb + rr * 128;
      bfr[nf] = *(const s16x8*)(p + (((g ^ (rr & 7)) * 16) ^ kx));
    }
    __builtin_amdgcn_s_setprio(1);
#pragma unroll
    for (int mf = 0; mf < 4; ++mf)
#pragma unroll
      for (int nf = 0; nf < 4; ++nf)
        acc[mf][nf] = MFMA16(af[mf], bfr[nf], acc[mf][nf]);
    __builtin_amdgcn_s_setprio(0);
  }
  // ---- ks-pair reduction: ks1 waves stash f32 acc in LDS (reuse Bs), ks0 sums+writes ----
  __syncthreads();
  float* scr = (float*)(&Bs[0][0]) + (wm * 2 + wn) * 4096;
  if (ksid == 1) {
#pragma unroll
    for (int mf = 0; mf < 4; ++mf)
#pragma unroll
      for (int nf = 0; nf < 4; ++nf) {
        const int col = nf * 16 + q15;
        *(f32x4*)&scr[col * 64 + ((mf * 16 + g * 4) ^ ((col & 7) << 3))] = acc[mf][nf];
      }
  }
  __syncthreads();
  if (ksid == 0) {
    u16* Pz = P + (size_t)z * NTOK * DD;
#pragma unroll
    for (int mf = 0; mf < 4; ++mf) {
      f32x4 sum[4];
#pragma unroll
      for (int nf = 0; nf < 4; ++nf) {
        const int col = nf * 16 + q15;
        const f32x4 o = *(const f32x4*)&scr[col * 64 + ((mf * 16 + g * 4) ^ ((col & 7) << 3))];
        sum[nf] = acc[mf][nf] + o;
      }
#pragma unroll
      for (int r = 0; r < 4; ++r) {
        const int srow = s0l + wm * 64 + mf * 16 + g * 4 + r;
        u16* orow = Pz + (size_t)(b * SS + srow) * DD + o0 + wn * 64;
#pragma unroll
        for (int nf = 0; nf < 4; ++nf)
          orow[nf * 16 + q15] = f2bf(sum[nf][r]);
      }
    }
  }
}

// ---------------- combine: x1 = gelu(P0+P1+cb) + x ----------------
__global__ void combine_kernel(const u16* __restrict__ P, const float* __restrict__ cb,
                               const float* __restrict__ x, float* __restrict__ x1) {
  const int idx = blockIdx.x * 256 + threadIdx.x;
  const size_t base = (size_t)idx * 4;
  const int col = (int)(base & (DD - 1));
  const u16x4 p0 = *(const u16x4*)(P + base);
  const u16x4 p1 = *(const u16x4*)(P + (size_t)NTOK * DD + base);
  const float4 xv = *(const float4*)(x + base);
  const float4 cbv = *(const float4*)(cb + col);
  float4 o;
  o.x = gelu_f(bf2f(p0[0]) + bf2f(p1[0]) + cbv.x) + xv.x;
  o.y = gelu_f(bf2f(p0[1]) + bf2f(p1[1]) + cbv.y) + xv.y;
  o.z = gelu_f(bf2f(p0[2]) + bf2f(p1[2]) + cbv.z) + xv.z;
  o.w = gelu_f(bf2f(p0[3]) + bf2f(p1[3]) + cbv.w) + xv.w;
  *(float4*)(x1 + base) = o;
}

// ---------------- qkv GEMM: qkvb[2048][3072] = hb @ inwb^T + in_b (bf16 out) ----------------
__global__ __launch_bounds__(256) void qkv_kernel(const u16* __restrict__ A, const u16* __restrict__ B,
                           const float* __restrict__ bias, u16* __restrict__ C) {
  const int n0 = blockIdx.x * 64, m0 = blockIdx.y * 128;
  const int tid = threadIdx.x, lane = tid & 63, w = tid >> 6;
  const int wm = w >> 1, wn = w & 1;
  __shared__ u16 As[2][128 * 64];
  __shared__ u16 Bs[2][64 * 64];
  f32x4 acc[4][2];
#pragma unroll
  for (int i = 0; i < 4; ++i)
#pragma unroll
    for (int j = 0; j < 2; ++j) acc[i][j] = f32x4{0.f, 0.f, 0.f, 0.f};
  auto stage = [&](int t, int buf) {
    const int k0 = t * 64;
#pragma unroll
    for (int q = 0; q < 4; ++q) {
      const int idx = w * 4 + q, r = idx * 8 + (lane >> 3), c = (lane & 7) ^ (r & 7);
      GLOAD16(A + (size_t)(m0 + r) * DD + k0 + c * 8, &As[buf][idx * 512]);
    }
#pragma unroll
    for (int q = 0; q < 2; ++q) {
      const int idx = w * 2 + q, r = idx * 8 + (lane >> 3), c = (lane & 7) ^ (r & 7);
      GLOAD16(B + (size_t)(n0 + r) * DD + k0 + c * 8, &Bs[buf][idx * 512]);
    }
  };
  stage(0, 0);
  asm volatile("s_waitcnt vmcnt(0)" ::: "memory");
  __syncthreads();
  const int T = DD / 64;
  for (int t = 0; t < T; ++t) {
    if (t + 1 < T) stage(t + 1, (t + 1) & 1);
    const u16* Ab = As[t & 1];
    const u16* Bb = Bs[t & 1];
    const int xb = (((lane >> 4) ^ (lane & 7)) * 16);
    s16x8 af[4][2], bfr[2][2];
#pragma unroll
    for (int mf = 0; mf < 4; ++mf) {
      const char* p = (const char*)Ab + (wm * 64 + mf * 16 + (lane & 15)) * 128;
      af[mf][0] = *(const s16x8*)(p + xb);
      af[mf][1] = *(const s16x8*)(p + (xb ^ 64));
    }
#pragma unroll
    for (int nf = 0; nf < 2; ++nf) {
      const char* p = (const char*)Bb + (wn * 32 + nf * 16 + (lane & 15)) * 128;
      bfr[nf][0] = *(const s16x8*)(p + xb);
      bfr[nf][1] = *(const s16x8*)(p + (xb ^ 64));
    }
#pragma unroll
    for (int ks = 0; ks < 2; ++ks)
#pragma unroll
      for (int mf = 0; mf < 4; ++mf)
#pragma unroll
        for (int nf = 0; nf < 2; ++nf)
          acc[mf][nf] = MFMA16(af[mf][ks], bfr[nf][ks], acc[mf][nf]);
    asm volatile("s_waitcnt vmcnt(0)" ::: "memory");
    __syncthreads();
  }
#pragma unroll
  for (int mf = 0; mf < 4; ++mf)
#pragma unroll
    for (int rr = 0; rr < 4; ++rr) {
      const int row = m0 + wm * 64 + mf * 16 + (lane >> 4) * 4 + rr;
#pragma unroll
      for (int nf = 0; nf < 2; ++nf) {
        const int col = n0 + wn * 32 + nf * 16 + (lane & 15);
        C[(size_t)row * D3 + col] = f2bf(acc[mf][nf][rr] + bias[col]);
      }
    }
}

// ---------------- out proj: x2 = ctxb @ outwb^T + out_b + x1 (f32 out + bf16 scatter to x2g) ----------------
__global__ __launch_bounds__(256) void out_kernel(const u16* __restrict__ A, const u16* __restrict__ B,
                           const float* __restrict__ bias, const float* __restrict__ resid,
                           float* __restrict__ C, u16* __restrict__ x2g,
                           const int* __restrict__ inv) {
  const int n0 = blockIdx.x * 64, m0 = blockIdx.y * 128;
  const int tid = threadIdx.x, lane = tid & 63, w = tid >> 6;
  const int wm = w >> 1, wn = w & 1;
  __shared__ u16 As[2][128 * 64];
  __shared__ u16 Bs[2][64 * 64];
  f32x4 acc[4][2];
#pragma unroll
  for (int i = 0; i < 4; ++i)
#pragma unroll
    for (int j = 0; j < 2; ++j) acc[i][j] = f32x4{0.f, 0.f, 0.f, 0.f};
  auto stage = [&](int t, int buf) {
    const int k0 = t * 64;
#pragma unroll
    for (int q = 0; q < 4; ++q) {
      const int idx = w * 4 + q, r = idx * 8 + (lane >> 3), c = (lane & 7) ^ (r & 7);
      GLOAD16(A + (size_t)(m0 + r) * DD + k0 + c * 8, &As[buf][idx * 512]);
    }
#pragma unroll
    for (int q = 0; q < 2; ++q) {
      const int idx = w * 2 + q, r = idx * 8 + (lane >> 3), c = (lane & 7) ^ (r & 7);
      GLOAD16(B + (size_t)(n0 + r) * DD + k0 + c * 8, &Bs[buf][idx * 512]);
    }
  };
  stage(0, 0);
  asm volatile("s_waitcnt vmcnt(0)" ::: "memory");
  __syncthreads();
  const int T = DD / 64;
  for (int t = 0; t < T; ++t) {
    if (t + 1 < T) stage(t + 1, (t + 1) & 1);
    const u16* Ab = As[t & 1];
    const u16* Bb = Bs[t & 1];
    const int xb = (((lane >> 4) ^ (lane & 7)) * 16);
    s16x8 af[4][2], bfr[2][2];
#pragma unroll
    for (int mf = 0; mf < 4; ++mf) {
      const char* p = (const char*)Ab + (wm * 64 + mf * 16 + (lane & 15)) * 128;
      af[mf][0] = *(const s16x8*)(p + xb);
      af[mf][1] = *(const s16x8*)(p + (xb ^ 64));
    }
#pragma unroll
    for (int nf = 0; nf < 2; ++nf) {
      const char* p = (const char*)Bb + (wn * 32 + nf * 16 + (lane & 15)) * 128;
      bfr[nf][0] = *(const s16x8*)(p + xb);
      bfr[nf][1] = *(const s16x8*)(p + (xb ^ 64));
    }
#pragma unroll
    for (int ks = 0; ks < 2; ++ks)
#pragma unroll
      for (int mf = 0; mf < 4; ++mf)
#pragma unroll
        for (int nf = 0; nf < 2; ++nf)
          acc[mf][nf] = MFMA16(af[mf][ks], bfr[nf][ks], acc[mf][nf]);
    asm volatile("s_waitcnt vmcnt(0)" ::: "memory");
    __syncthreads();
  }
#pragma unroll
  for (int mf = 0; mf < 4; ++mf)
#pragma unroll
    for (int rr = 0; rr < 4; ++rr) {
      const int row = m0 + wm * 64 + mf * 16 + (lane >> 4) * 4 + rr;
      const int slot = inv[row];
#pragma unroll
      for (int nf = 0; nf < 2; ++nf) {
        const int col = n0 + wn * 32 + nf * 16 + (lane & 15);
        const float v = acc[mf][nf][rr] + bias[col] + resid[(size_t)row * DD + col];
        C[(size_t)row * DD + col] = v;
        x2g[(size_t)slot * DD + col] = f2bf(v);
      }
    }
}

// ---------------- MFMA flash attention: 128 q x (b,h) per block, 8 waves x 16 q ----------------
__global__ __launch_bounds__(512) void attn_kernel(const u16* __restrict__ qkv,
                                                   const u16* __restrict__ Vt,
                                                   u16* __restrict__ ctx) {
  const int q0 = blockIdx.x * 128, h = blockIdx.y, b = blockIdx.z;
  const int tid = threadIdx.x, lane = tid & 63, w = tid >> 6;
  const int q15 = lane & 15, g = lane >> 4, l7 = lane & 7;
  __shared__ u16 Q_lds[128 * 64];
  __shared__ u16 K_lds[2][64 * 64];
  __shared__ u16 V_lds[2][64 * 64];
  __shared__ u16 P_lds[8][16 * 72];
  __shared__ float s_lds[8][16];

#pragma unroll
  for (int q2 = 0; q2 < 2; ++q2) {
    const int idx = w * 2 + q2;
    const int r = idx * 8 + (lane >> 3);
    const int c = l7 ^ (r & 7);
    GLOAD16(qkv + (size_t)(b * SS + q0 + r) * D3 + h * HDIM + c * 8, &Q_lds[idx * 512]);
  }
  auto stageK = [&](int buf, int kt) {
    const int r = w * 8 + (lane >> 3);
    const int c = l7 ^ (r & 7);
    GLOAD16(qkv + (size_t)(b * SS + kt * 64 + r) * D3 + DD + h * HDIM + c * 8,
            &K_lds[buf][w * 512]);
  };
  auto stageV = [&](int buf, int kt) {
    const int r = w * 8 + (lane >> 3);
    const int c = l7 ^ (r & 7);
    GLOAD16(Vt + ((size_t)(b * HH + h) * HDIM + r) * SS + kt * 64 + c * 8,
            &V_lds[buf][w * 512]);
  };
  stageK(0, 0);
  stageV(0, 0);
  asm volatile("s_waitcnt vmcnt(0)" ::: "memory");
  __syncthreads();
  s16x8 bq[2];
#pragma unroll
  for (int ks = 0; ks < 2; ++ks)
    bq[ks] = *(const s16x8*)((const char*)Q_lds + (w * 16 + q15) * 128 + ((4 * ks + g) ^ l7) * 16);
  f32x4 oacc[4];
#pragma unroll
  for (int nf = 0; nf < 4; ++nf) oacc[nf] = f32x4{0.f, 0.f, 0.f, 0.f};
  float mrun = -3.0e38f, lrun = 0.0f;
  int buf = 0;
  for (int kt = 0; kt < 16; ++kt) {
    if (kt < 15) { stageK(buf ^ 1, kt + 1); stageV(buf ^ 1, kt + 1); }
    f32x4 st[4];
#pragma unroll
    for (int mf = 0; mf < 4; ++mf) st[mf] = f32x4{0.f, 0.f, 0.f, 0.f};
#pragma unroll
    for (int ks = 0; ks < 2; ++ks) {
#pragma unroll
      for (int mf = 0; mf < 4; ++mf) {
        const s16x8 ka = *(const s16x8*)((const char*)K_lds[buf] + (mf * 16 + q15) * 128 +
                                         ((4 * ks + g) ^ l7) * 16);
        st[mf] = MFMA16(ka, bq[ks], st[mf]);
      }
    }
    float t0[4][4];
    float cmax = -3.0e38f;
#pragma unroll
    for (int mf = 0; mf < 4; ++mf)
#pragma unroll
      for (int r = 0; r < 4; ++r) {
        const float v = st[mf][r] * 0.125f;
        t0[mf][r] = v;
        cmax = fmaxf(cmax, v);
      }
    cmax = fmaxf(cmax, __shfl_xor(cmax, 16));
    cmax = fmaxf(cmax, __shfl_xor(cmax, 32));
    const float mnew = fmaxf(mrun, cmax);
    const float scf = __expf(mrun - mnew);
    float psum = 0.f;
#pragma unroll
    for (int mf = 0; mf < 4; ++mf)
#pragma unroll
      for (int r = 0; r < 4; ++r) {
        const float p = __expf(t0[mf][r] - mnew);
        t0[mf][r] = p;
        psum += p;
      }
    psum += __shfl_xor(psum, 16);
    psum += __shfl_xor(psum, 32);
    lrun = lrun * scf + psum;
    mrun = mnew;
    s_lds[w][q15] = scf;
    u16* pw = &P_lds[w][0];
#pragma unroll
    for (int mf = 0; mf < 4; ++mf) {
      u32x2 pk;
      pk[0] = (unsigned)f2bf(t0[mf][0]) | ((unsigned)f2bf(t0[mf][1]) << 16);
      pk[1] = (unsigned)f2bf(t0[mf][2]) | ((unsigned)f2bf(t0[mf][3]) << 16);
      *(u32x2*)(pw + q15 * 72 + mf * 16 + g * 4) = pk;
    }
    asm volatile("s_waitcnt lgkmcnt(0)" ::: "memory");
    const f32x4 scv = *(const f32x4*)&s_lds[w][g * 4];
#pragma unroll
    for (int nf = 0; nf < 4; ++nf)
#pragma unroll
      for (int r = 0; r < 4; ++r) oacc[nf][r] *= scv[r];
#pragma unroll
    for (int ks = 0; ks < 2; ++ks) {
      const s16x8 pa = *(const s16x8*)(pw + q15 * 72 + ks * 32 + g * 8);
#pragma unroll
      for (int nf = 0; nf < 4; ++nf) {
        const s16x8 bv = *(const s16x8*)((const char*)V_lds[buf] + (nf * 16 + q15) * 128 +
                                         ((4 * ks + g) ^ l7) * 16);
        oacc[nf] = MFMA16(pa, bv, oacc[nf]);
      }
    }
    asm volatile("s_waitcnt vmcnt(0)" ::: "memory");
    __syncthreads();
    buf ^= 1;
  }
  const float linv = 1.0f / lrun;
  s_lds[w][q15] = linv;
  asm volatile("s_waitcnt lgkmcnt(0)" ::: "memory");
  const f32x4 lv = *(const f32x4*)&s_lds[w][g * 4];
#pragma unroll
  for (int nf = 0; nf < 4; ++nf)
#pragma unroll
    for (int r = 0; r < 4; ++r) {
      const int qg = q0 + w * 16 + g * 4 + r;
      ctx[(size_t)(b * SS + qg) * DD + h * HDIM + nf * 16 + q15] = f2bf(oacc[nf][r] * lv[r]);
    }
}

// ---------------- MoE routing ----------------
__global__ void zero_counts_kernel(int* c) { if (threadIdx.x < GG) c[threadIdx.x] = 0; }

__global__ void gather_kernel(const int* __restrict__ gid, int* __restrict__ counts,
                              int* __restrict__ gather) {
  const int n = blockIdx.x * 256 + threadIdx.x;
  if (n < NTOK) {
    const int g = gid[n];
    const int slot = atomicAdd(&counts[g], 1);
    gather[g * NTOK + slot] = n;
  }
}

// off[g] = exclusive prefix sum of counts; off[GG] = NTOK
__global__ void scan_kernel(const int* __restrict__ cnts, int* __restrict__ off) {
  if (threadIdx.x == 0) {
    int s = 0;
#pragma unroll
    for (int g = 0; g < GG; ++g) { off[g] = s; s += cnts[g]; }
    off[GG] = s;
  }
}

// gidx[off[g]+slot] = tok ; inv[tok] = off[g]+slot
__global__ void pack_kernel(const int* __restrict__ gat, const int* __restrict__ cnts,
                            const int* __restrict__ off, int* __restrict__ gidx,
                            int* __restrict__ inv) {
  const int g = blockIdx.y;
  const int slot = blockIdx.x * 256 + threadIdx.x;
  if (slot < cnts[g]) {
    const int tok = gat[g * NTOK + slot];
    const int sg = off[g] + slot;
    gidx[sg] = tok;
    inv[tok] = sg;
  }
}

// ---------------- MoE GEMM1: h1[e][base+slot] = gelu(x2g[base+slot] @ w1t[g,e]^T + b1) ----------------
// grid x = n-tile (dense -> all XCD residues active), y = m-tile (sparse early-exit).
__global__ __launch_bounds__(256) void moe1_kernel(const u16* __restrict__ x2g, const u16* __restrict__ w1t,
                            const float* __restrict__ e_b1, const int* __restrict__ off,
                            const int* __restrict__ cnts, u16* __restrict__ h1) {
  const int ge = blockIdx.z, g = ge >> 1, e = ge & 1;
  const int cnt = cnts[g];
  const int m0 = blockIdx.y * 128;
  if (m0 >= cnt) return;
  const int base = off[g];
  const int n0 = blockIdx.x * 64;
  const u16* A = x2g + (size_t)base * DD;       // contiguous rows of this group
  const u16* B = w1t + (size_t)ge * HIDN * DD;  // [HID][D]
  const int tid = threadIdx.x, lane = tid & 63, w = tid >> 6;
  const int wm = w >> 1, wn = w & 1;
  __shared__ u16 As[2][128 * 64];
  __shared__ u16 Bs[2][64 * 64];
  f32x4 acc[4][2];
#pragma unroll
  for (int i = 0; i < 4; ++i)
#pragma unroll
    for (int j = 0; j < 2; ++j) acc[i][j] = f32x4{0.f, 0.f, 0.f, 0.f};
  auto stage = [&](int t, int buf) {
    const int k0 = t * 64;
#pragma unroll
    for (int q = 0; q < 4; ++q) {
      const int idx = w * 4 + q, r = idx * 8 + (lane >> 3), c = (lane & 7) ^ (r & 7);
      int rg = m0 + r; if (rg > cnt - 1) rg = cnt - 1;
      GLOAD16(A + (size_t)rg * DD + k0 + c * 8, &As[buf][idx * 512]);
    }
#pragma unroll
    for (int q = 0; q < 2; ++q) {
      const int idx = w * 2 + q, r = idx * 8 + (lane >> 3), c = (lane & 7) ^ (r & 7);
      GLOAD16(B + (size_t)(n0 + r) * DD + k0 + c * 8, &Bs[buf][idx * 512]);
    }
  };
  stage(0, 0);
  asm volatile("s_waitcnt vmcnt(0)" ::: "memory");
  __syncthreads();
  const int T = DD / 64;
  for (int t = 0; t < T; ++t) {
    if (t + 1 < T) stage(t + 1, (t + 1) & 1);
    const u16* Ab = As[t & 1];
    const u16* Bb = Bs[t & 1];
    const int xb = (((lane >> 4) ^ (lane & 7)) * 16);
    s16x8 af[4][2], bfr[2][2];
#pragma unroll
    for (int mf = 0; mf < 4; ++mf) {
      const char* p = (const char*)Ab + (wm * 64 + mf * 16 + (lane & 15)) * 128;
      af[mf][0] = *(const s16x8*)(p + xb);
      af[mf][1] = *(const s16x8*)(p + (xb ^ 64));
    }
#pragma unroll
    for (int nf = 0; nf < 2; ++nf) {
      const char* p = (const char*)Bb + (wn * 32 + nf * 16 + (lane & 15)) * 128;
      bfr[nf][0] = *(const s16x8*)(p + xb);
      bfr[nf][1] = *(const s16x8*)(p + (xb ^ 64));
    }
#pragma unroll
    for (int ks = 0; ks < 2; ++ks)
#pragma unroll
      for (int mf = 0; mf < 4; ++mf)
#pragma unroll
        for (int nf = 0; nf < 2; ++nf)
          acc[mf][nf] = MFMA16(af[mf][ks], bfr[nf][ks], acc[mf][nf]);
    asm volatile("s_waitcnt vmcnt(0)" ::: "memory");
    __syncthreads();
  }
  const float* b1 = e_b1 + (size_t)ge * HIDN;
#pragma unroll
  for (int mf = 0; mf < 4; ++mf)
#pragma unroll
    for (int rr = 0; rr < 4; ++rr) {
      const int rowg = m0 + wm * 64 + mf * 16 + (lane >> 4) * 4 + rr;
      if (rowg < cnt) {
        u16* orow = h1 + ((size_t)e * NTOK + base + rowg) * HIDN;  // slot-ordered
#pragma unroll
        for (int nf = 0; nf < 2; ++nf) {
          const int col = n0 + wn * 32 + nf * 16 + (lane & 15);
          orow[col] = f2bf(gelu_f(acc[mf][nf][rr] + b1[col]));
        }
      }
    }
}

// ---------------- MoE GEMM2: out[tok] = 0.5*sum_e h1[e][slot] @ w2t[g,e]^T + 0.5*(b2_0+b2_1) + x2 ----------------
// grid x = n-tile (dense), y = m-tile (sparse early-exit); scatter only in the epilogue.
__global__ __launch_bounds__(256) void moe2_kernel(const u16* __restrict__ h1, const u16* __restrict__ w2t,
                            const float* __restrict__ e_b2, const int* __restrict__ off,
                            const int* __restrict__ cnts, const int* __restrict__ gidx,
                            const float* __restrict__ x2, float* __restrict__ outp) {
  const int g = blockIdx.z;
  const int cnt = cnts[g];
  const int m0 = blockIdx.y * 128;
  if (m0 >= cnt) return;
  const int base = off[g];
  const int n0 = blockIdx.x * 64;
  const int tid = threadIdx.x, lane = tid & 63, w = tid >> 6;
  const int wm = w >> 1, wn = w & 1;
  __shared__ u16 As[2][128 * 64];
  __shared__ u16 Bs[2][64 * 64];
  f32x4 acc[4][2];
#pragma unroll
  for (int i = 0; i < 4; ++i)
#pragma unroll
    for (int j = 0; j < 2; ++j) acc[i][j] = f32x4{0.f, 0.f, 0.f, 0.f};
  auto stage = [&](int t, int buf) {
    const int e = t >> 5;
    const int k0 = (t & 31) * 64;
#pragma unroll
    for (int q = 0; q < 4; ++q) {
      const int idx = w * 4 + q, r = idx * 8 + (lane >> 3), c = (lane & 7) ^ (r & 7);
      int rg = m0 + r; if (rg > cnt - 1) rg = cnt - 1;
      GLOAD16(h1 + ((size_t)e * NTOK + base + rg) * HIDN + k0 + c * 8, &As[buf][idx * 512]);
    }
#pragma unroll
    for (int q = 0; q < 2; ++q) {
      const int idx = w * 2 + q, r = idx * 8 + (lane >> 3), c = (lane & 7) ^ (r & 7);
      GLOAD16(w2t + ((size_t)(g * EE + e) * DD + n0 + r) * HIDN + k0 + c * 8, &Bs[buf][idx * 512]);
    }
  };
  stage(0, 0);
  asm volatile("s_waitcnt vmcnt(0)" ::: "memory");
  __syncthreads();
  const int T = 64;
  for (int t = 0; t < T; ++t) {
    if (t + 1 < T) stage(t + 1, (t + 1) & 1);
    const u16* Ab = As[t & 1];
    const u16* Bb = Bs[t & 1];
    const int xb = (((lane >> 4) ^ (lane & 7)) * 16);
    s16x8 af[4][2], bfr[2][2];
#pragma unroll
    for (int mf = 0; mf < 4; ++mf) {
      const char* p = (const char*)Ab + (wm * 64 + mf * 16 + (lane & 15)) * 128;
      af[mf][0] = *(const s16x8*)(p + xb);
      af[mf][1] = *(const s16x8*)(p + (xb ^ 64));
    }
#pragma unroll
    for (int nf = 0; nf < 2; ++nf) {
      const char* p = (const char*)Bb + (wn * 32 + nf * 16 + (lane & 15)) * 128;
      bfr[nf][0] = *(const s16x8*)(p + xb);
      bfr[nf][1] = *(const s16x8*)(p + (xb ^ 64));
    }
#pragma unroll
    for (int ks = 0; ks < 2; ++ks)
#pragma unroll
      for (int mf = 0; mf < 4; ++mf)
#pragma unroll
        for (int nf = 0; nf < 2; ++nf)
          acc[mf][nf] = MFMA16(af[mf][ks], bfr[nf][ks], acc[mf][nf]);
    asm volatile("s_waitcnt vmcnt(0)" ::: "memory");
    __syncthreads();
  }
  const float* b20 = e_b2 + (size_t)(g * EE + 0) * DD;
  const float* b21 = e_b2 + (size_t)(g * EE + 1) * DD;
#pragma unroll
  for (int mf = 0; mf < 4; ++mf)
#pragma unroll
    for (int rr = 0; rr < 4; ++rr) {
      const int rowg = m0 + wm * 64 + mf * 16 + (lane >> 4) * 4 + rr;
      if (rowg < cnt) {
        const int tok = gidx[base + rowg];
#pragma unroll
        for (int nf = 0; nf < 2; ++nf) {
          const int col = n0 + wn * 32 + nf * 16 + (lane & 15);
          outp[(size_t)tok * DD + col] =
              0.5f * acc[mf][nf][rr] + 0.5f * (b20[col] + b21[col]) + x2[(size_t)tok * DD + col];
        }
      }
    }
}

extern "C" void kernel_launch(void* const* d_in, const int* in_sizes, int n_in,
                              void* d_out, int out_size, void* d_ws, size_t ws_size,
                              hipStream_t stream) {
  (void)in_sizes; (void)n_in; (void)out_size; (void)ws_size;
  const float* x      = (const float*)d_in[0];
  const int*   gid    = (const int*)d_in[1];
  const float* cn_g   = (const float*)d_in[2];
  const float* cn_b   = (const float*)d_in[3];
  const float* conv_w = (const float*)d_in[4];
  const float* conv_b = (const float*)d_in[5];
  const float* an_g   = (const float*)d_in[6];
  const float* an_b   = (const float*)d_in[7];
  const float* in_w   = (const float*)d_in[8];
  const float* in_b   = (const float*)d_in[9];
  const float* out_w  = (const float*)d_in[10];
  const float* out_b  = (const float*)d_in[11];
  const float* e_w1   = (const float*)d_in[12];
  const float* e_b1   = (const float*)d_in[13];
  const float* e_w2   = (const float*)d_in[14];
  const float* e_b2   = (const float*)d_in[15];
  float* outp = (float*)d_out;

  // ---- workspace map (high-water 74MB + ~41KB, same tail as r3-pass) ----
  // conv phase: hb 0..4 | Pc 4..12 | Wb 12..74 (62MB, dead after conv_kernel)
  // post-conv:  x1 12..20 | qkvb 24..36 | inwb 40..46 | outwb 40..42 | Vt 46..50
  //             x2 52..60 | inv 60..60.008 (in dead-Wb hole) | x2g 64..68
  // MoE phase:  wgt 4..36 | h1 36..52 | tail at 74M: gat/cnts/offp/gidx
  // ROUTING RUNS AFTER CONV (r4 crash: prep_convw clobbered inv placed inside Wb's span).
  char* wsp = (char*)d_ws;
  u16*   hb    = (u16*)(wsp);                         // 0..4M  (ln out; ctxb reuse)
  u16*   Pc    = (u16*)(wsp + (4ull << 20));          // 4..12M (conv partials x2, conv phase)
  float* x1    = (float*)(wsp + (12ull << 20));       // 12..20M (combine out)
  u16*   Wb    = (u16*)(wsp + (12ull << 20));         // 12..74M (conv phase only)
  u16*   qkvb  = (u16*)(wsp + (24ull << 20));         // 24..36M (qkv->attn)
  u16*   inwb  = (u16*)(wsp + (40ull << 20));         // 40..46M (qkv phase)
  u16*   outwb = (u16*)(wsp + (40ull << 20));         // 40..42M (out phase, after qkv)
  u16*   Vt    = (u16*)(wsp + (46ull << 20));         // 46..50M (attn phase)
  u16*   ctxb  = hb;                                  // 0..4M  (after qkv)
  float* x2    = (float*)(wsp + (52ull << 20));       // 52..60M
  int*   inv   = (int*)(wsp + (60ull << 20));         // 60M.. 8KB (tok->slot; written post-conv)
  u16*   x2g   = (u16*)(wsp + (64ull << 20));         // 64..68M (slot-packed tokens)
  u16*   wgt   = (u16*)(wsp + (4ull << 20));          // 4..36M (w1t, then w2t; MoE phase)
  u16*   h1    = (u16*)(wsp + (36ull << 20));         // 36..52M (MoE phase, slot-ordered)
  int*   gat   = (int*)(wsp + (74ull << 20));         // 32KB
  int*   cnts  = gat + GG * NTOK;                     // 16B
  int*   offp  = cnts + GG;                           // 20B
  int*   gidx  = offp + (GG + 1);                     // 8KB

  // ---- conv block (v2, measured 208us) ----
  ln_kernel<<<NTOK, 256, 0, stream>>>(x, cn_g, cn_b, hb);
  prep_convw<<<1024, 256, 0, stream>>>(conv_w, Wb);
  conv_kernel<<<256, 512, 0, stream>>>(hb, Wb, Pc);
  combine_kernel<<<NTOK * DD / 1024, 256, 0, stream>>>(Pc, conv_b, x, x1);
  // ---- routing (Wb now dead; inv lives in its hole; needed by out_kernel) ----
  zero_counts_kernel<<<1, 64, 0, stream>>>(cnts);
  gather_kernel<<<NTOK / 256, 256, 0, stream>>>(gid, cnts, gat);
  scan_kernel<<<1, 64, 0, stream>>>(cnts, offp);
  pack_kernel<<<dim3(NTOK / 256, GG), 256, 0, stream>>>(gat, cnts, offp, gidx, inv);
  // ---- attention block ----
  ln_kernel<<<NTOK, 256, 0, stream>>>(x1, an_g, an_b, hb);
  cvt_kernel<<<3072, 256, 0, stream>>>(in_w, inwb, 3 * DD * DD / 4);
  qkv_kernel<<<dim3(D3 / 64, NTOK / 128), 256, 0, stream>>>(hb, inwb, in_b, qkvb);
  vtr_kernel<<<dim3(SS / 32, HDIM / 32, BB * HH), 256, 0, stream>>>(qkvb, Vt);
  attn_kernel<<<dim3(SS / 128, HH, BB), 512, 0, stream>>>(qkvb, Vt, ctxb);
  cvt_kernel<<<1024, 256, 0, stream>>>(out_w, outwb, DD * DD / 4);
  out_kernel<<<dim3(DD / 64, NTOK / 128), 256, 0, stream>>>(ctxb, outwb, out_b, x1, x2, x2g, inv);
  // ---- MoE (slot-packed + dense-fastest grids: all 8 XCDs active) ----
  tr_kernel<<<dim3(HIDN / 32, DD / 32, GG * EE), 256, 0, stream>>>(e_w1, wgt, DD, HIDN);
  moe1_kernel<<<dim3(HIDN / 64, NTOK / 128, GG * EE), 256, 0, stream>>>(x2g, wgt, e_b1, offp, cnts, h1);
  tr_kernel<<<dim3(DD / 32, HIDN / 32, GG * EE), 256, 0, stream>>>(e_w2, wgt, HIDN, DD);
  moe2_kernel<<<dim3(DD / 64, NTOK / 128, GG), 256, 0, stream>>>(h1, wgt, e_b2, offp, cnts, gidx, x2, outp);
}

// Round 6
// 493.414 us; speedup vs baseline: 1.4482x; 1.0672x over previous
//
#include <hip/hip_runtime.h>
#include <hip/hip_bf16.h>
#include <math.h>

#define BB 2
#define SS 1024
#define DD 1024
#define HH 16
#define HDIM 64
#define KK 31
#define GG 4
#define EE 2
#define HIDN 2048
#define NTOK (BB*SS)
#define D3 (3*DD)

typedef unsigned short u16;
typedef __attribute__((ext_vector_type(8))) short s16x8;
typedef __attribute__((ext_vector_type(8))) unsigned short u16x8;
typedef __attribute__((ext_vector_type(4))) unsigned short u16x4;
typedef __attribute__((ext_vector_type(4))) float f32x4;
typedef __attribute__((ext_vector_type(2))) unsigned int u32x2;

__device__ __forceinline__ float gelu_f(float x) {
  return 0.5f * x * (1.0f + erff(x * 0.7071067811865475f));
}
__device__ __forceinline__ u16 f2bf(float f) {
  unsigned u = __builtin_bit_cast(unsigned, f);
  u = (u + 0x7fffu + ((u >> 16) & 1u)) >> 16;
  return (u16)u;
}
__device__ __forceinline__ float bf2f(u16 u) {
  return __builtin_bit_cast(float, ((unsigned)u) << 16);
}
__device__ __forceinline__ f32x4 MFMA16(s16x8 a, s16x8 b, f32x4 c) {
  return __builtin_amdgcn_mfma_f32_16x16x32_bf16(a, b, c, 0, 0, 0);
}
#define GLOAD16(gp, lp) __builtin_amdgcn_global_load_lds( \
    (const __attribute__((address_space(1))) void*)(gp),  \
    (__attribute__((address_space(3))) void*)(lp), 16, 0, 0)

// ---------------- LayerNorm: fp32 in -> bf16 out, one block per row ----------------
__global__ void ln_kernel(const float* __restrict__ x, const float* __restrict__ g,
                          const float* __restrict__ b, u16* __restrict__ out) {
  const int row = blockIdx.x;
  const int tid = threadIdx.x;
  __shared__ float red[4];
  const float4 v = reinterpret_cast<const float4*>(x + (size_t)row * DD)[tid];
  float s = v.x + v.y + v.z + v.w;
  s += __shfl_down(s, 32); s += __shfl_down(s, 16); s += __shfl_down(s, 8);
  s += __shfl_down(s, 4);  s += __shfl_down(s, 2);  s += __shfl_down(s, 1);
  if ((tid & 63) == 0) red[tid >> 6] = s;
  __syncthreads();
  const float mean = (red[0] + red[1] + red[2] + red[3]) * (1.0f / DD);
  __syncthreads();
  const float4 d = make_float4(v.x - mean, v.y - mean, v.z - mean, v.w - mean);
  float sq = d.x*d.x + d.y*d.y + d.z*d.z + d.w*d.w;
  sq += __shfl_down(sq, 32); sq += __shfl_down(sq, 16); sq += __shfl_down(sq, 8);
  sq += __shfl_down(sq, 4);  sq += __shfl_down(sq, 2);  sq += __shfl_down(sq, 1);
  if ((tid & 63) == 0) red[tid >> 6] = sq;
  __syncthreads();
  const float var = (red[0] + red[1] + red[2] + red[3]) * (1.0f / DD);
  const float rstd = rsqrtf(var + 1e-5f);
  const float4 gv = reinterpret_cast<const float4*>(g)[tid];
  const float4 bv = reinterpret_cast<const float4*>(b)[tid];
  u16x4 o;
  o[0] = f2bf(d.x * rstd * gv.x + bv.x);
  o[1] = f2bf(d.y * rstd * gv.y + bv.y);
  o[2] = f2bf(d.z * rstd * gv.z + bv.z);
  o[3] = f2bf(d.w * rstd * gv.w + bv.w);
  *reinterpret_cast<u16x4*>(out + (size_t)row * DD + tid * 4) = o;
}

// ---------------- conv weight reorder: conv_w[o][i][k] f32 -> Wb[k][o][i] bf16 ----------------
__global__ void prep_convw(const float* __restrict__ cw, u16* __restrict__ Wb) {
  const int o = blockIdx.x;
#pragma unroll
  for (int rep = 0; rep < 4; ++rep) {
    const int i = rep * 256 + threadIdx.x;
    const float* src = cw + ((size_t)o * DD + i) * KK;
    float wv[KK];
#pragma unroll
    for (int k = 0; k < KK; ++k) wv[k] = src[k];
#pragma unroll
    for (int k = 0; k < KK; ++k)
      Wb[((size_t)k * DD + o) * DD + i] = f2bf(wv[k]);
  }
}

// ---------------- plain f32 -> bf16 convert ----------------
__global__ void cvt_kernel(const float* __restrict__ in, u16* __restrict__ outp, int n4) {
  const int i = blockIdx.x * 256 + threadIdx.x;
  if (i < n4) {
    const float4 v = reinterpret_cast<const float4*>(in)[i];
    u16x4 o; o[0] = f2bf(v.x); o[1] = f2bf(v.y); o[2] = f2bf(v.z); o[3] = f2bf(v.w);
    reinterpret_cast<u16x4*>(outp)[i] = o;
  }
}

// ---------------- transpose-convert: src[z][R][C] f32 -> dst[z][C][R] bf16 ----------------
__global__ void tr_kernel(const float* __restrict__ src, u16* __restrict__ dst, int R, int C) {
  __shared__ float tile[32][33];
  const int c0 = blockIdx.x * 32, r0 = blockIdx.y * 32;
  const size_t base = (size_t)blockIdx.z * R * C;
  const int tx = threadIdx.x & 31, ty = threadIdx.x >> 5;  // ty 0..7
#pragma unroll
  for (int i = 0; i < 4; ++i)
    tile[ty + i * 8][tx] = src[base + (size_t)(r0 + ty + i * 8) * C + c0 + tx];
  __syncthreads();
#pragma unroll
  for (int i = 0; i < 4; ++i)
    dst[base + (size_t)(c0 + ty + i * 8) * R + r0 + tx] = f2bf(tile[tx][ty + i * 8]);
}

// ---------------- V transpose: qkvb V-part -> Vt[b][h][d][k] bf16 ----------------
__global__ void vtr_kernel(const u16* __restrict__ qkvb, u16* __restrict__ Vt) {
  __shared__ u16 tile[32][40];
  const int k0 = blockIdx.x * 32, d0 = blockIdx.y * 32, bh = blockIdx.z;
  const int b = bh >> 4, h = bh & 15;
  const int tx = threadIdx.x & 31, ty = threadIdx.x >> 5;  // ty 0..7
#pragma unroll
  for (int i = 0; i < 4; ++i)
    tile[ty + i * 8][tx] =
        qkvb[(size_t)(b * SS + k0 + ty + i * 8) * D3 + 2 * DD + h * HDIM + d0 + tx];
  __syncthreads();
#pragma unroll
  for (int i = 0; i < 4; ++i)
    Vt[((size_t)(b * HH + h) * HDIM + d0 + ty + i * 8) * SS + k0 + tx] = tile[tx][ty + i * 8];
}

// ---------------- conv via MFMA v4: 2 taps per sync unit, B ring-6 ----------------
// Same 128s x 128o tile / 8-wave 2(s)x2(o)x2(ks) layout as v2 (measured 208us), but the
// barrier+vmcnt quantum is now 2 taps (32 MFMA/wave) instead of 1 (16): sync units 248->128.
// Ring-6 B (96KB) keeps >=2 barriers between a slot's last ds_read and its next DMA write
// (ring-4 would race at 2-tap granularity). LDS 136KB, still 1 block/CU, 2 waves/SIMD.
__global__ __launch_bounds__(512) void conv_kernel(const u16* __restrict__ hb,
                                                   const u16* __restrict__ Wb,
                                                   u16* __restrict__ P) {
  const int L = blockIdx.x;            // 0..255
  const int o_t = L & 7;               // o-tile pinned per XCD (B L2 reuse)
  const int rest = L >> 3;
  const int s_t = rest >> 1;           // 0..15
  const int z = rest & 1;              // i-half
  const int b = s_t >> 3, sloc = s_t & 7;
  const int s0l = sloc * 128;
  const int o0 = o_t * 128;
  const int ibase = z * 512;
  const int tid = threadIdx.x, lane = tid & 63, w = tid >> 6;
  const int wm = (w >> 2) & 1, wn = (w >> 1) & 1, ksid = w & 1;
  const int q15 = lane & 15, g = lane >> 4;
  __shared__ __align__(16) u16 Ad[2][160 * 64];   // 40 KB, dbuf over i-slices
  __shared__ __align__(16) u16 Bs[6][128 * 64];   // 96 KB, shared ring-6
  const int rlo = (sloc == 0) ? 15 : 0;
  const int rhi = (sloc == 7) ? 143 : 158;
  if (sloc == 0)
    for (int i = tid; i < 15 * 64; i += 512) { Ad[0][i] = 0; Ad[1][i] = 0; }
  if (sloc == 7)
    for (int i = tid; i < 17 * 64; i += 512) { Ad[0][143 * 64 + i] = 0; Ad[1][143 * 64 + i] = 0; }
  auto stageA = [&](int buf, int i0) {
    for (int q = w; q < 20; q += 8) {
      const int r = q * 8 + (lane >> 3);
      const int c = (lane & 7) ^ (r & 7);
      if (r >= rlo && r < rhi)
        GLOAD16(hb + (size_t)(b * SS + s0l - 15 + r) * DD + i0 + c * 8, &Ad[buf][q * 512]);
    }
  };
  auto stageB = [&](int slot, int k, int i0) {  // 128o x 64i, 2 gloads/wave
#pragma unroll
    for (int qq = 0; qq < 2; ++qq) {
      const int q = w * 2 + qq;
      const int r = q * 8 + (lane >> 3);        // 0..127 o-row
      const int c = (lane & 7) ^ (r & 7);
      GLOAD16(Wb + ((size_t)k * DD + o0 + r) * DD + i0 + c * 8, &Bs[slot][q * 512]);
    }
  };
  f32x4 acc[4][4];
#pragma unroll
  for (int i = 0; i < 4; ++i)
#pragma unroll
    for (int j = 0; j < 4; ++j) acc[i][j] = f32x4{0.f, 0.f, 0.f, 0.f};
  stageA(0, ibase);
  stageB(0, 0, ibase);
  stageB(1, 1, ibase);
  asm volatile("s_waitcnt vmcnt(0)" ::: "memory");
  __builtin_amdgcn_s_barrier();
  asm volatile("" ::: "memory");
  const int T = 8 * KK;  // 248 taps total
  const int kx = ksid * 64;  // byte XOR selecting this wave's K=32 half (swizzle-compatible)
  for (int i0i = 0; i0i < 8; ++i0i) {
    const u16* Ab = Ad[i0i & 1];
    for (int k0 = 0; k0 < KK; k0 += 2) {       // 15 pairs + 1 singleton per slice
      const int t = i0i * KK + k0;
      const bool two = (k0 + 1 < KK);
      // prefetch B for taps t+2 (and t+3 if pair), global-t ring-6
      {
        int tn = t + 2;
        if (tn < T) stageB(tn % 6, tn % KK, ibase + (tn / KK) * 64);
        if (two) {
          tn = t + 3;
          if (tn < T) stageB(tn % 6, tn % KK, ibase + (tn / KK) * 64);
        }
      }
      // A-frag reads for both taps (independent of in-flight B)
      s16x8 af[4], af2[4];
      const int rk0 = wm * 64 + q15 + k0;
#pragma unroll
      for (int mf = 0; mf < 4; ++mf) {
        const int rr = rk0 + mf * 16;
        const char* p = (const char*)Ab + rr * 128;
        af[mf] = *(const s16x8*)(p + (((g ^ (rr & 7)) * 16) ^ kx));
      }
      if (two) {
#pragma unroll
        for (int mf = 0; mf < 4; ++mf) {
          const int rr = rk0 + 1 + mf * 16;
          const char* p = (const char*)Ab + rr * 128;
          af2[mf] = *(const s16x8*)(p + (((g ^ (rr & 7)) * 16) ^ kx));
        }
      }
      // wait: allow the (up to 2) future taps' loads to stay in flight
      const int t_end = t + (two ? 1 : 0);
      const int fut = T - 1 - t_end;           // future taps still to consume
      if (fut >= 2)      asm volatile("s_waitcnt vmcnt(4)" ::: "memory");
      else if (fut == 1) asm volatile("s_waitcnt vmcnt(2)" ::: "memory");
      else               asm volatile("s_waitcnt vmcnt(0)" ::: "memory");
      __builtin_amdgcn_s_barrier();            // all waves' B(t..t_end) visible
      asm volatile("" ::: "memory");
      // A prefetch AFTER the wait+barrier so the counted vmcnt never waits on a fresh load
      if (k0 == 4 && i0i < 7) stageA((i0i + 1) & 1, ibase + (i0i + 1) * 64);
      const u16* Bb = Bs[t % 6];
      s16x8 bfr[4], bfr2[4];
#pragma unroll
      for (int nf = 0; nf < 4; ++nf) {
        const int rr = wn * 64 + nf * 16 + q15;
        const char* p = (const char*)Bb + rr * 128;
        bfr[nf] = *(const s16x8*)(p + (((g ^ (rr & 7)) * 16) ^ kx));
      }
      if (two) {
        const u16* Bb2 = Bs[(t + 1) % 6];
#pragma unroll
        for (int nf = 0; nf < 4; ++nf) {
          const int rr = wn * 64 + nf * 16 + q15;
          const char* p = (const char*)Bb2 + rr * 128;
          bfr2[nf] = *(const s16x8*)(p + (((g ^ (rr & 7)) * 16) ^ kx));
        }
      }
      __builtin_amdgcn_s_setprio(1);
#pragma unroll
      for (int mf = 0; mf < 4; ++mf)
#pragma unroll
        for (int nf = 0; nf < 4; ++nf)
          acc[mf][nf] = MFMA16(af[mf], bfr[nf], acc[mf][nf]);
      if (two) {
#pragma unroll
        for (int mf = 0; mf < 4; ++mf)
#pragma unroll
          for (int nf = 0; nf < 4; ++nf)
            acc[mf][nf] = MFMA16(af2[mf], bfr2[nf], acc[mf][nf]);
      }
      __builtin_amdgcn_s_setprio(0);
      if (k0 + 2 >= KK && i0i < 7) {           // slice boundary: A buffer swap
        asm volatile("s_waitcnt vmcnt(0)" ::: "memory");
        __syncthreads();
      }
    }
  }
  // ---- ks-pair reduction: ks1 waves stash f32 acc in LDS (reuse Bs), ks0 sums+writes ----
  __syncthreads();
  float* scr = (float*)(&Bs[0][0]) + (wm * 2 + wn) * 4096;
  if (ksid == 1) {
#pragma unroll
    for (int mf = 0; mf < 4; ++mf)
#pragma unroll
      for (int nf = 0; nf < 4; ++nf) {
        const int col = nf * 16 + q15;
        *(f32x4*)&scr[col * 64 + ((mf * 16 + g * 4) ^ ((col & 7) << 3))] = acc[mf][nf];
      }
  }
  __syncthreads();
  if (ksid == 0) {
    u16* Pz = P + (size_t)z * NTOK * DD;
#pragma unroll
    for (int mf = 0; mf < 4; ++mf) {
      f32x4 sum[4];
#pragma unroll
      for (int nf = 0; nf < 4; ++nf) {
        const int col = nf * 16 + q15;
        const f32x4 o = *(const f32x4*)&scr[col * 64 + ((mf * 16 + g * 4) ^ ((col & 7) << 3))];
        sum[nf] = acc[mf][nf] + o;
      }
#pragma unroll
      for (int r = 0; r < 4; ++r) {
        const int srow = s0l + wm * 64 + mf * 16 + g * 4 + r;
        u16* orow = Pz + (size_t)(b * SS + srow) * DD + o0 + wn * 64;
#pragma unroll
        for (int nf = 0; nf < 4; ++nf)
          orow[nf * 16 + q15] = f2bf(sum[nf][r]);
      }
    }
  }
}

// ---------------- combine: x1 = gelu(P0+P1+cb) + x ----------------
__global__ void combine_kernel(const u16* __restrict__ P, const float* __restrict__ cb,
                               const float* __restrict__ x, float* __restrict__ x1) {
  const int idx = blockIdx.x * 256 + threadIdx.x;
  const size_t base = (size_t)idx * 4;
  const int col = (int)(base & (DD - 1));
  const u16x4 p0 = *(const u16x4*)(P + base);
  const u16x4 p1 = *(const u16x4*)(P + (size_t)NTOK * DD + base);
  const float4 xv = *(const float4*)(x + base);
  const float4 cbv = *(const float4*)(cb + col);
  float4 o;
  o.x = gelu_f(bf2f(p0[0]) + bf2f(p1[0]) + cbv.x) + xv.x;
  o.y = gelu_f(bf2f(p0[1]) + bf2f(p1[1]) + cbv.y) + xv.y;
  o.z = gelu_f(bf2f(p0[2]) + bf2f(p1[2]) + cbv.z) + xv.z;
  o.w = gelu_f(bf2f(p0[3]) + bf2f(p1[3]) + cbv.w) + xv.w;
  *(float4*)(x1 + base) = o;
}

// ---------------- qkv GEMM: qkvb[2048][3072] = hb @ inwb^T + in_b (bf16 out) ----------------
__global__ __launch_bounds__(256) void qkv_kernel(const u16* __restrict__ A, const u16* __restrict__ B,
                           const float* __restrict__ bias, u16* __restrict__ C) {
  const int n0 = blockIdx.x * 64, m0 = blockIdx.y * 128;
  const int tid = threadIdx.x, lane = tid & 63, w = tid >> 6;
  const int wm = w >> 1, wn = w & 1;
  __shared__ u16 As[2][128 * 64];
  __shared__ u16 Bs[2][64 * 64];
  f32x4 acc[4][2];
#pragma unroll
  for (int i = 0; i < 4; ++i)
#pragma unroll
    for (int j = 0; j < 2; ++j) acc[i][j] = f32x4{0.f, 0.f, 0.f, 0.f};
  auto stage = [&](int t, int buf) {
    const int k0 = t * 64;
#pragma unroll
    for (int q = 0; q < 4; ++q) {
      const int idx = w * 4 + q, r = idx * 8 + (lane >> 3), c = (lane & 7) ^ (r & 7);
      GLOAD16(A + (size_t)(m0 + r) * DD + k0 + c * 8, &As[buf][idx * 512]);
    }
#pragma unroll
    for (int q = 0; q < 2; ++q) {
      const int idx = w * 2 + q, r = idx * 8 + (lane >> 3), c = (lane & 7) ^ (r & 7);
      GLOAD16(B + (size_t)(n0 + r) * DD + k0 + c * 8, &Bs[buf][idx * 512]);
    }
  };
  stage(0, 0);
  asm volatile("s_waitcnt vmcnt(0)" ::: "memory");
  __syncthreads();
  const int T = DD / 64;
  for (int t = 0; t < T; ++t) {
    if (t + 1 < T) stage(t + 1, (t + 1) & 1);
    const u16* Ab = As[t & 1];
    const u16* Bb = Bs[t & 1];
    const int xb = (((lane >> 4) ^ (lane & 7)) * 16);
    s16x8 af[4][2], bfr[2][2];
#pragma unroll
    for (int mf = 0; mf < 4; ++mf) {
      const char* p = (const char*)Ab + (wm * 64 + mf * 16 + (lane & 15)) * 128;
      af[mf][0] = *(const s16x8*)(p + xb);
      af[mf][1] = *(const s16x8*)(p + (xb ^ 64));
    }
#pragma unroll
    for (int nf = 0; nf < 2; ++nf) {
      const char* p = (const char*)Bb + (wn * 32 + nf * 16 + (lane & 15)) * 128;
      bfr[nf][0] = *(const s16x8*)(p + xb);
      bfr[nf][1] = *(const s16x8*)(p + (xb ^ 64));
    }
#pragma unroll
    for (int ks = 0; ks < 2; ++ks)
#pragma unroll
      for (int mf = 0; mf < 4; ++mf)
#pragma unroll
        for (int nf = 0; nf < 2; ++nf)
          acc[mf][nf] = MFMA16(af[mf][ks], bfr[nf][ks], acc[mf][nf]);
    asm volatile("s_waitcnt vmcnt(0)" ::: "memory");
    __syncthreads();
  }
#pragma unroll
  for (int mf = 0; mf < 4; ++mf)
#pragma unroll
    for (int rr = 0; rr < 4; ++rr) {
      const int row = m0 + wm * 64 + mf * 16 + (lane >> 4) * 4 + rr;
#pragma unroll
      for (int nf = 0; nf < 2; ++nf) {
        const int col = n0 + wn * 32 + nf * 16 + (lane & 15);
        C[(size_t)row * D3 + col] = f2bf(acc[mf][nf][rr] + bias[col]);
      }
    }
}

// ---------------- out proj: x2 = ctxb @ outwb^T + out_b + x1 (f32 out + bf16 scatter to x2g) ----------------
__global__ __launch_bounds__(256) void out_kernel(const u16* __restrict__ A, const u16* __restrict__ B,
                           const float* __restrict__ bias, const float* __restrict__ resid,
                           float* __restrict__ C, u16* __restrict__ x2g,
                           const int* __restrict__ inv) {
  const int n0 = blockIdx.x * 64, m0 = blockIdx.y * 128;
  const int tid = threadIdx.x, lane = tid & 63, w = tid >> 6;
  const int wm = w >> 1, wn = w & 1;
  __shared__ u16 As[2][128 * 64];
  __shared__ u16 Bs[2][64 * 64];
  f32x4 acc[4][2];
#pragma unroll
  for (int i = 0; i < 4; ++i)
#pragma unroll
    for (int j = 0; j < 2; ++j) acc[i][j] = f32x4{0.f, 0.f, 0.f, 0.f};
  auto stage = [&](int t, int buf) {
    const int k0 = t * 64;
#pragma unroll
    for (int q = 0; q < 4; ++q) {
      const int idx = w * 4 + q, r = idx * 8 + (lane >> 3), c = (lane & 7) ^ (r & 7);
      GLOAD16(A + (size_t)(m0 + r) * DD + k0 + c * 8, &As[buf][idx * 512]);
    }
#pragma unroll
    for (int q = 0; q < 2; ++q) {
      const int idx = w * 2 + q, r = idx * 8 + (lane >> 3), c = (lane & 7) ^ (r & 7);
      GLOAD16(B + (size_t)(n0 + r) * DD + k0 + c * 8, &Bs[buf][idx * 512]);
    }
  };
  stage(0, 0);
  asm volatile("s_waitcnt vmcnt(0)" ::: "memory");
  __syncthreads();
  const int T = DD / 64;
  for (int t = 0; t < T; ++t) {
    if (t + 1 < T) stage(t + 1, (t + 1) & 1);
    const u16* Ab = As[t & 1];
    const u16* Bb = Bs[t & 1];
    const int xb = (((lane >> 4) ^ (lane & 7)) * 16);
    s16x8 af[4][2], bfr[2][2];
#pragma unroll
    for (int mf = 0; mf < 4; ++mf) {
      const char* p = (const char*)Ab + (wm * 64 + mf * 16 + (lane & 15)) * 128;
      af[mf][0] = *(const s16x8*)(p + xb);
      af[mf][1] = *(const s16x8*)(p + (xb ^ 64));
    }
#pragma unroll
    for (int nf = 0; nf < 2; ++nf) {
      const char* p = (const char*)Bb + (wn * 32 + nf * 16 + (lane & 15)) * 128;
      bfr[nf][0] = *(const s16x8*)(p + xb);
      bfr[nf][1] = *(const s16x8*)(p + (xb ^ 64));
    }
#pragma unroll
    for (int ks = 0; ks < 2; ++ks)
#pragma unroll
      for (int mf = 0; mf < 4; ++mf)
#pragma unroll
        for (int nf = 0; nf < 2; ++nf)
          acc[mf][nf] = MFMA16(af[mf][ks], bfr[nf][ks], acc[mf][nf]);
    asm volatile("s_waitcnt vmcnt(0)" ::: "memory");
    __syncthreads();
  }
#pragma unroll
  for (int mf = 0; mf < 4; ++mf)
#pragma unroll
    for (int rr = 0; rr < 4; ++rr) {
      const int row = m0 + wm * 64 + mf * 16 + (lane >> 4) * 4 + rr;
      const int slot = inv[row];
#pragma unroll
      for (int nf = 0; nf < 2; ++nf) {
        const int col = n0 + wn * 32 + nf * 16 + (lane & 15);
        const float v = acc[mf][nf][rr] + bias[col] + resid[(size_t)row * DD + col];
        C[(size_t)row * DD + col] = v;
        x2g[(size_t)slot * DD + col] = f2bf(v);
      }
    }
}

// ---------------- MFMA flash attention: 128 q x (b,h) per block, 8 waves x 16 q ----------------
__global__ __launch_bounds__(512) void attn_kernel(const u16* __restrict__ qkv,
                                                   const u16* __restrict__ Vt,
                                                   u16* __restrict__ ctx) {
  const int q0 = blockIdx.x * 128, h = blockIdx.y, b = blockIdx.z;
  const int tid = threadIdx.x, lane = tid & 63, w = tid >> 6;
  const int q15 = lane & 15, g = lane >> 4, l7 = lane & 7;
  __shared__ u16 Q_lds[128 * 64];
  __shared__ u16 K_lds[2][64 * 64];
  __shared__ u16 V_lds[2][64 * 64];
  __shared__ u16 P_lds[8][16 * 72];
  __shared__ float s_lds[8][16];

#pragma unroll
  for (int q2 = 0; q2 < 2; ++q2) {
    const int idx = w * 2 + q2;
    const int r = idx * 8 + (lane >> 3);
    const int c = l7 ^ (r & 7);
    GLOAD16(qkv + (size_t)(b * SS + q0 + r) * D3 + h * HDIM + c * 8, &Q_lds[idx * 512]);
  }
  auto stageK = [&](int buf, int kt) {
    const int r = w * 8 + (lane >> 3);
    const int c = l7 ^ (r & 7);
    GLOAD16(qkv + (size_t)(b * SS + kt * 64 + r) * D3 + DD + h * HDIM + c * 8,
            &K_lds[buf][w * 512]);
  };
  auto stageV = [&](int buf, int kt) {
    const int r = w * 8 + (lane >> 3);
    const int c = l7 ^ (r & 7);
    GLOAD16(Vt + ((size_t)(b * HH + h) * HDIM + r) * SS + kt * 64 + c * 8,
            &V_lds[buf][w * 512]);
  };
  stageK(0, 0);
  stageV(0, 0);
  asm volatile("s_waitcnt vmcnt(0)" ::: "memory");
  __syncthreads();
  s16x8 bq[2];
#pragma unroll
  for (int ks = 0; ks < 2; ++ks)
    bq[ks] = *(const s16x8*)((const char*)Q_lds + (w * 16 + q15) * 128 + ((4 * ks + g) ^ l7) * 16);
  f32x4 oacc[4];
#pragma unroll
  for (int nf = 0; nf < 4; ++nf) oacc[nf] = f32x4{0.f, 0.f, 0.f, 0.f};
  float mrun = -3.0e38f, lrun = 0.0f;
  int buf = 0;
  for (int kt = 0; kt < 16; ++kt) {
    if (kt < 15) { stageK(buf ^ 1, kt + 1); stageV(buf ^ 1, kt + 1); }
    f32x4 st[4];
#pragma unroll
    for (int mf = 0; mf < 4; ++mf) st[mf] = f32x4{0.f, 0.f, 0.f, 0.f};
#pragma unroll
    for (int ks = 0; ks < 2; ++ks) {
#pragma unroll
      for (int mf = 0; mf < 4; ++mf) {
        const s16x8 ka = *(const s16x8*)((const char*)K_lds[buf] + (mf * 16 + q15) * 128 +
                                         ((4 * ks + g) ^ l7) * 16);
        st[mf] = MFMA16(ka, bq[ks], st[mf]);
      }
    }
    float t0[4][4];
    float cmax = -3.0e38f;
#pragma unroll
    for (int mf = 0; mf < 4; ++mf)
#pragma unroll
      for (int r = 0; r < 4; ++r) {
        const float v = st[mf][r] * 0.125f;
        t0[mf][r] = v;
        cmax = fmaxf(cmax, v);
      }
    cmax = fmaxf(cmax, __shfl_xor(cmax, 16));
    cmax = fmaxf(cmax, __shfl_xor(cmax, 32));
    const float mnew = fmaxf(mrun, cmax);
    const float scf = __expf(mrun - mnew);
    float psum = 0.f;
#pragma unroll
    for (int mf = 0; mf < 4; ++mf)
#pragma unroll
      for (int r = 0; r < 4; ++r) {
        const float p = __expf(t0[mf][r] - mnew);
        t0[mf][r] = p;
        psum += p;
      }
    psum += __shfl_xor(psum, 16);
    psum += __shfl_xor(psum, 32);
    lrun = lrun * scf + psum;
    mrun = mnew;
    s_lds[w][q15] = scf;
    u16* pw = &P_lds[w][0];
#pragma unroll
    for (int mf = 0; mf < 4; ++mf) {
      u32x2 pk;
      pk[0] = (unsigned)f2bf(t0[mf][0]) | ((unsigned)f2bf(t0[mf][1]) << 16);
      pk[1] = (unsigned)f2bf(t0[mf][2]) | ((unsigned)f2bf(t0[mf][3]) << 16);
      *(u32x2*)(pw + q15 * 72 + mf * 16 + g * 4) = pk;
    }
    asm volatile("s_waitcnt lgkmcnt(0)" ::: "memory");
    const f32x4 scv = *(const f32x4*)&s_lds[w][g * 4];
#pragma unroll
    for (int nf = 0; nf < 4; ++nf)
#pragma unroll
      for (int r = 0; r < 4; ++r) oacc[nf][r] *= scv[r];
#pragma unroll
    for (int ks = 0; ks < 2; ++ks) {
      const s16x8 pa = *(const s16x8*)(pw + q15 * 72 + ks * 32 + g * 8);
#pragma unroll
      for (int nf = 0; nf < 4; ++nf) {
        const s16x8 bv = *(const s16x8*)((const char*)V_lds[buf] + (nf * 16 + q15) * 128 +
                                         ((4 * ks + g) ^ l7) * 16);
        oacc[nf] = MFMA16(pa, bv, oacc[nf]);
      }
    }
    asm volatile("s_waitcnt vmcnt(0)" ::: "memory");
    __syncthreads();
    buf ^= 1;
  }
  const float linv = 1.0f / lrun;
  s_lds[w][q15] = linv;
  asm volatile("s_waitcnt lgkmcnt(0)" ::: "memory");
  const f32x4 lv = *(const f32x4*)&s_lds[w][g * 4];
#pragma unroll
  for (int nf = 0; nf < 4; ++nf)
#pragma unroll
    for (int r = 0; r < 4; ++r) {
      const int qg = q0 + w * 16 + g * 4 + r;
      ctx[(size_t)(b * SS + qg) * DD + h * HDIM + nf * 16 + q15] = f2bf(oacc[nf][r] * lv[r]);
    }
}

// ---------------- MoE routing ----------------
__global__ void zero_counts_kernel(int* c) { if (threadIdx.x < GG) c[threadIdx.x] = 0; }

__global__ void gather_kernel(const int* __restrict__ gid, int* __restrict__ counts,
                              int* __restrict__ gather) {
  const int n = blockIdx.x * 256 + threadIdx.x;
  if (n < NTOK) {
    const int g = gid[n];
    const int slot = atomicAdd(&counts[g], 1);
    gather[g * NTOK + slot] = n;
  }
}

// off[g] = exclusive prefix sum of counts; off[GG] = NTOK
__global__ void scan_kernel(const int* __restrict__ cnts, int* __restrict__ off) {
  if (threadIdx.x == 0) {
    int s = 0;
#pragma unroll
    for (int g = 0; g < GG; ++g) { off[g] = s; s += cnts[g]; }
    off[GG] = s;
  }
}

// gidx[off[g]+slot] = tok ; inv[tok] = off[g]+slot
__global__ void pack_kernel(const int* __restrict__ gat, const int* __restrict__ cnts,
                            const int* __restrict__ off, int* __restrict__ gidx,
                            int* __restrict__ inv) {
  const int g = blockIdx.y;
  const int slot = blockIdx.x * 256 + threadIdx.x;
  if (slot < cnts[g]) {
    const int tok = gat[g * NTOK + slot];
    const int sg = off[g] + slot;
    gidx[sg] = tok;
    inv[tok] = sg;
  }
}

// ---------------- MoE GEMM1: h1[e][base+slot] = gelu(x2g[base+slot] @ w1t[g,e]^T + b1) ----------------
// grid x = n-tile (dense -> all XCD residues active), y = m-tile (sparse early-exit).
__global__ __launch_bounds__(256) void moe1_kernel(const u16* __restrict__ x2g, const u16* __restrict__ w1t,
                            const float* __restrict__ e_b1, const int* __restrict__ off,
                            const int* __restrict__ cnts, u16* __restrict__ h1) {
  const int ge = blockIdx.z, g = ge >> 1, e = ge & 1;
  const int cnt = cnts[g];
  const int m0 = blockIdx.y * 128;
  if (m0 >= cnt) return;
  const int base = off[g];
  const int n0 = blockIdx.x * 64;
  const u16* A = x2g + (size_t)base * DD;       // contiguous rows of this group
  const u16* B = w1t + (size_t)ge * HIDN * DD;  // [HID][D]
  const int tid = threadIdx.x, lane = tid & 63, w = tid >> 6;
  const int wm = w >> 1, wn = w & 1;
  __shared__ u16 As[2][128 * 64];
  __shared__ u16 Bs[2][64 * 64];
  f32x4 acc[4][2];
#pragma unroll
  for (int i = 0; i < 4; ++i)
#pragma unroll
    for (int j = 0; j < 2; ++j) acc[i][j] = f32x4{0.f, 0.f, 0.f, 0.f};
  auto stage = [&](int t, int buf) {
    const int k0 = t * 64;
#pragma unroll
    for (int q = 0; q < 4; ++q) {
      const int idx = w * 4 + q, r = idx * 8 + (lane >> 3), c = (lane & 7) ^ (r & 7);
      int rg = m0 + r; if (rg > cnt - 1) rg = cnt - 1;
      GLOAD16(A + (size_t)rg * DD + k0 + c * 8, &As[buf][idx * 512]);
    }
#pragma unroll
    for (int q = 0; q < 2; ++q) {
      const int idx = w * 2 + q, r = idx * 8 + (lane >> 3), c = (lane & 7) ^ (r & 7);
      GLOAD16(B + (size_t)(n0 + r) * DD + k0 + c * 8, &Bs[buf][idx * 512]);
    }
  };
  stage(0, 0);
  asm volatile("s_waitcnt vmcnt(0)" ::: "memory");
  __syncthreads();
  const int T = DD / 64;
  for (int t = 0; t < T; ++t) {
    if (t + 1 < T) stage(t + 1, (t + 1) & 1);
    const u16* Ab = As[t & 1];
    const u16* Bb = Bs[t & 1];
    const int xb = (((lane >> 4) ^ (lane & 7)) * 16);
    s16x8 af[4][2], bfr[2][2];
#pragma unroll
    for (int mf = 0; mf < 4; ++mf) {
      const char* p = (const char*)Ab + (wm * 64 + mf * 16 + (lane & 15)) * 128;
      af[mf][0] = *(const s16x8*)(p + xb);
      af[mf][1] = *(const s16x8*)(p + (xb ^ 64));
    }
#pragma unroll
    for (int nf = 0; nf < 2; ++nf) {
      const char* p = (const char*)Bb + (wn * 32 + nf * 16 + (lane & 15)) * 128;
      bfr[nf][0] = *(const s16x8*)(p + xb);
      bfr[nf][1] = *(const s16x8*)(p + (xb ^ 64));
    }
#pragma unroll
    for (int ks = 0; ks < 2; ++ks)
#pragma unroll
      for (int mf = 0; mf < 4; ++mf)
#pragma unroll
        for (int nf = 0; nf < 2; ++nf)
          acc[mf][nf] = MFMA16(af[mf][ks], bfr[nf][ks], acc[mf][nf]);
    asm volatile("s_waitcnt vmcnt(0)" ::: "memory");
    __syncthreads();
  }
  const float* b1 = e_b1 + (size_t)ge * HIDN;
#pragma unroll
  for (int mf = 0; mf < 4; ++mf)
#pragma unroll
    for (int rr = 0; rr < 4; ++rr) {
      const int rowg = m0 + wm * 64 + mf * 16 + (lane >> 4) * 4 + rr;
      if (rowg < cnt) {
        u16* orow = h1 + ((size_t)e * NTOK + base + rowg) * HIDN;  // slot-ordered
#pragma unroll
        for (int nf = 0; nf < 2; ++nf) {
          const int col = n0 + wn * 32 + nf * 16 + (lane & 15);
          orow[col] = f2bf(gelu_f(acc[mf][nf][rr] + b1[col]));
        }
      }
    }
}

// ---------------- MoE GEMM2: out[tok] = 0.5*sum_e h1[e][slot] @ w2t[g,e]^T + 0.5*(b2_0+b2_1) + x2 ----------------
// grid x = n-tile (dense), y = m-tile (sparse early-exit); scatter only in the epilogue.
__global__ __launch_bounds__(256) void moe2_kernel(const u16* __restrict__ h1, const u16* __restrict__ w2t,
                            const float* __restrict__ e_b2, const int* __restrict__ off,
                            const int* __restrict__ cnts, const int* __restrict__ gidx,
                            const float* __restrict__ x2, float* __restrict__ outp) {
  const int g = blockIdx.z;
  const int cnt = cnts[g];
  const int m0 = blockIdx.y * 128;
  if (m0 >= cnt) return;
  const int base = off[g];
  const int n0 = blockIdx.x * 64;
  const int tid = threadIdx.x, lane = tid & 63, w = tid >> 6;
  const int wm = w >> 1, wn = w & 1;
  __shared__ u16 As[2][128 * 64];
  __shared__ u16 Bs[2][64 * 64];
  f32x4 acc[4][2];
#pragma unroll
  for (int i = 0; i < 4; ++i)
#pragma unroll
    for (int j = 0; j < 2; ++j) acc[i][j] = f32x4{0.f, 0.f, 0.f, 0.f};
  auto stage = [&](int t, int buf) {
    const int e = t >> 5;
    const int k0 = (t & 31) * 64;
#pragma unroll
    for (int q = 0; q < 4; ++q) {
      const int idx = w * 4 + q, r = idx * 8 + (lane >> 3), c = (lane & 7) ^ (r & 7);
      int rg = m0 + r; if (rg > cnt - 1) rg = cnt - 1;
      GLOAD16(h1 + ((size_t)e * NTOK + base + rg) * HIDN + k0 + c * 8, &As[buf][idx * 512]);
    }
#pragma unroll
    for (int q = 0; q < 2; ++q) {
      const int idx = w * 2 + q, r = idx * 8 + (lane >> 3), c = (lane & 7) ^ (r & 7);
      GLOAD16(w2t + ((size_t)(g * EE + e) * DD + n0 + r) * HIDN + k0 + c * 8, &Bs[buf][idx * 512]);
    }
  };
  stage(0, 0);
  asm volatile("s_waitcnt vmcnt(0)" ::: "memory");
  __syncthreads();
  const int T = 64;
  for (int t = 0; t < T; ++t) {
    if (t + 1 < T) stage(t + 1, (t + 1) & 1);
    const u16* Ab = As[t & 1];
    const u16* Bb = Bs[t & 1];
    const int xb = (((lane >> 4) ^ (lane & 7)) * 16);
    s16x8 af[4][2], bfr[2][2];
#pragma unroll
    for (int mf = 0; mf < 4; ++mf) {
      const char* p = (const char*)Ab + (wm * 64 + mf * 16 + (lane & 15)) * 128;
      af[mf][0] = *(const s16x8*)(p + xb);
      af[mf][1] = *(const s16x8*)(p + (xb ^ 64));
    }
#pragma unroll
    for (int nf = 0; nf < 2; ++nf) {
      const char* p = (const char*)Bb + (wn * 32 + nf * 16 + (lane & 15)) * 128;
      bfr[nf][0] = *(const s16x8*)(p + xb);
      bfr[nf][1] = *(const s16x8*)(p + (xb ^ 64));
    }
#pragma unroll
    for (int ks = 0; ks < 2; ++ks)
#pragma unroll
      for (int mf = 0; mf < 4; ++mf)
#pragma unroll
        for (int nf = 0; nf < 2; ++nf)
          acc[mf][nf] = MFMA16(af[mf][ks], bfr[nf][ks], acc[mf][nf]);
    asm volatile("s_waitcnt vmcnt(0)" ::: "memory");
    __syncthreads();
  }
  const float* b20 = e_b2 + (size_t)(g * EE + 0) * DD;
  const float* b21 = e_b2 + (size_t)(g * EE + 1) * DD;
#pragma unroll
  for (int mf = 0; mf < 4; ++mf)
#pragma unroll
    for (int rr = 0; rr < 4; ++rr) {
      const int rowg = m0 + wm * 64 + mf * 16 + (lane >> 4) * 4 + rr;
      if (rowg < cnt) {
        const int tok = gidx[base + rowg];
#pragma unroll
        for (int nf = 0; nf < 2; ++nf) {
          const int col = n0 + wn * 32 + nf * 16 + (lane & 15);
          outp[(size_t)tok * DD + col] =
              0.5f * acc[mf][nf][rr] + 0.5f * (b20[col] + b21[col]) + x2[(size_t)tok * DD + col];
        }
      }
    }
}

extern "C" void kernel_launch(void* const* d_in, const int* in_sizes, int n_in,
                              void* d_out, int out_size, void* d_ws, size_t ws_size,
                              hipStream_t stream) {
  (void)in_sizes; (void)n_in; (void)out_size; (void)ws_size;
  const float* x      = (const float*)d_in[0];
  const int*   gid    = (const int*)d_in[1];
  const float* cn_g   = (const float*)d_in[2];
  const float* cn_b   = (const float*)d_in[3];
  const float* conv_w = (const float*)d_in[4];
  const float* conv_b = (const float*)d_in[5];
  const float* an_g   = (const float*)d_in[6];
  const float* an_b   = (const float*)d_in[7];
  const float* in_w   = (const float*)d_in[8];
  const float* in_b   = (const float*)d_in[9];
  const float* out_w  = (const float*)d_in[10];
  const float* out_b  = (const float*)d_in[11];
  const float* e_w1   = (const float*)d_in[12];
  const float* e_b1   = (const float*)d_in[13];
  const float* e_w2   = (const float*)d_in[14];
  const float* e_b2   = (const float*)d_in[15];
  float* outp = (float*)d_out;

  // ---- workspace map (high-water 74MB + ~41KB, identical to r5-pass) ----
  // conv phase: hb 0..4 | Pc 4..12 | Wb 12..74 (dead after conv_kernel)
  // post-conv:  x1 12..20 | qkvb 24..36 | inwb 40..46 | outwb 40..42 | Vt 46..50
  //             x2 52..60 | inv 60..60.008 (in dead-Wb hole) | x2g 64..68
  // MoE phase:  wgt 4..36 | h1 36..52 | tail at 74M: gat/cnts/offp/gidx
  // ROUTING RUNS AFTER CONV (r4 lesson: prep_convw clobbers anything inside Wb's span).
  char* wsp = (char*)d_ws;
  u16*   hb    = (u16*)(wsp);                         // 0..4M  (ln out; ctxb reuse)
  u16*   Pc    = (u16*)(wsp + (4ull << 20));          // 4..12M (conv partials x2, conv phase)
  float* x1    = (float*)(wsp + (12ull << 20));       // 12..20M (combine out)
  u16*   Wb    = (u16*)(wsp + (12ull << 20));         // 12..74M (conv phase only)
  u16*   qkvb  = (u16*)(wsp + (24ull << 20));         // 24..36M (qkv->attn)
  u16*   inwb  = (u16*)(wsp + (40ull << 20));         // 40..46M (qkv phase)
  u16*   outwb = (u16*)(wsp + (40ull << 20));         // 40..42M (out phase, after qkv)
  u16*   Vt    = (u16*)(wsp + (46ull << 20));         // 46..50M (attn phase)
  u16*   ctxb  = hb;                                  // 0..4M  (after qkv)
  float* x2    = (float*)(wsp + (52ull << 20));       // 52..60M
  int*   inv   = (int*)(wsp + (60ull << 20));         // 60M.. 8KB (tok->slot; written post-conv)
  u16*   x2g   = (u16*)(wsp + (64ull << 20));         // 64..68M (slot-packed tokens)
  u16*   wgt   = (u16*)(wsp + (4ull << 20));          // 4..36M (w1t, then w2t; MoE phase)
  u16*   h1    = (u16*)(wsp + (36ull << 20));         // 36..52M (MoE phase, slot-ordered)
  int*   gat   = (int*)(wsp + (74ull << 20));         // 32KB
  int*   cnts  = gat + GG * NTOK;                     // 16B
  int*   offp  = cnts + GG;                           // 20B
  int*   gidx  = offp + (GG + 1);                     // 8KB

  // ---- conv block (v4: 2 taps/sync-unit, ring-6) ----
  ln_kernel<<<NTOK, 256, 0, stream>>>(x, cn_g, cn_b, hb);
  prep_convw<<<1024, 256, 0, stream>>>(conv_w, Wb);
  conv_kernel<<<256, 512, 0, stream>>>(hb, Wb, Pc);
  combine_kernel<<<NTOK * DD / 1024, 256, 0, stream>>>(Pc, conv_b, x, x1);
  // ---- routing (Wb now dead; inv lives in its hole; needed by out_kernel) ----
  zero_counts_kernel<<<1, 64, 0, stream>>>(cnts);
  gather_kernel<<<NTOK / 256, 256, 0, stream>>>(gid, cnts, gat);
  scan_kernel<<<1, 64, 0, stream>>>(cnts, offp);
  pack_kernel<<<dim3(NTOK / 256, GG), 256, 0, stream>>>(gat, cnts, offp, gidx, inv);
  // ---- attention block ----
  ln_kernel<<<NTOK, 256, 0, stream>>>(x1, an_g, an_b, hb);
  cvt_kernel<<<3072, 256, 0, stream>>>(in_w, inwb, 3 * DD * DD / 4);
  qkv_kernel<<<dim3(D3 / 64, NTOK / 128), 256, 0, stream>>>(hb, inwb, in_b, qkvb);
  vtr_kernel<<<dim3(SS / 32, HDIM / 32, BB * HH), 256, 0, stream>>>(qkvb, Vt);
  attn_kernel<<<dim3(SS / 128, HH, BB), 512, 0, stream>>>(qkvb, Vt, ctxb);
  cvt_kernel<<<1024, 256, 0, stream>>>(out_w, outwb, DD * DD / 4);
  out_kernel<<<dim3(DD / 64, NTOK / 128), 256, 0, stream>>>(ctxb, outwb, out_b, x1, x2, x2g, inv);
  // ---- MoE (slot-packed + dense-fastest grids: all 8 XCDs active) ----
  tr_kernel<<<dim3(HIDN / 32, DD / 32, GG * EE), 256, 0, stream>>>(e_w1, wgt, DD, HIDN);
  moe1_kernel<<<dim3(HIDN / 64, NTOK / 128, GG * EE), 256, 0, stream>>>(x2g, wgt, e_b1, offp, cnts, h1);
  tr_kernel<<<dim3(DD / 32, HIDN / 32, GG * EE), 256, 0, stream>>>(e_w2, wgt, HIDN, DD);
  moe2_kernel<<<dim3(DD / 64, NTOK / 128, GG), 256, 0, stream>>>(h1, wgt, e_b2, offp, cnts, gidx, x2, outp);
}